// Round 8
// baseline (493.631 us; speedup 1.0000x reference)
//
#include <hip/hip_runtime.h>
#include <stdint.h>
#include <stddef.h>

typedef _Float16 half_t;
typedef _Float16 half8 __attribute__((ext_vector_type(8)));
typedef float float4v __attribute__((ext_vector_type(4)));

#define D_DIM 1792
#define B_DIM 8192
#define LD D_DIM

// ---------------------------------------------------------------------------
// Async global->LDS staging of ROWS*32 fp16 tile (rows along K, NT layout).
// slot = chunk ^ ((row>>1)&3): conflict-free (verified SQ_LDS_BANK_CONFLICT=0).
// ---------------------------------------------------------------------------
__device__ __forceinline__ void stage_rows(const half_t* __restrict__ src, int row0, int ld,
                                           int k0, half_t* dst, int nchunks, int tid) {
  for (int base = 0; base < nchunks; base += 256) {
    int ch  = base + tid;
    int row = ch >> 2, kc = ch & 3;
    int swz = kc ^ ((row >> 1) & 3);
    const half_t* g = src + (size_t)(row0 + row) * ld + k0 + swz * 8;
    half_t* l = dst + (size_t)(base + (tid & 192)) * 8;   // wave-uniform base; HW adds lane*16B
    __builtin_amdgcn_global_load_lds(
        (const __attribute__((address_space(1))) uint32_t*)(const void*)g,
        (__attribute__((address_space(3))) uint32_t*)(void*)l, 16, 0, 0);
  }
}

// FULL-LINE staging (128B/row = one aligned L2 line). slot = kc ^ (row&7).
__device__ __forceinline__ void stage_rows64(const half_t* __restrict__ src, int row0, int ld,
                                             int k0, half_t* dst, int nchunks, int tid) {
  for (int base = 0; base < nchunks; base += 256) {
    int ch  = base + tid;
    int row = ch >> 3, kc = ch & 7;
    int swz = kc ^ (row & 7);
    const half_t* g = src + (size_t)(row0 + row) * ld + k0 + swz * 8;
    half_t* l = dst + (size_t)(base + (tid & 192)) * 8;
    __builtin_amdgcn_global_load_lds(
        (const __attribute__((address_space(1))) uint32_t*)(const void*)g,
        (__attribute__((address_space(3))) uint32_t*)(void*)l, 16, 0, 0);
  }
}

__device__ __forceinline__ half8 frag32(const half_t* lds, int row, int chunk) {
  int slot = chunk ^ ((row >> 1) & 3);
  return *(const half8*)(lds + row * 32 + slot * 8);
}
__device__ __forceinline__ half8 frag64(const half_t* lds, int row, int chunk) {
  int slot = chunk ^ (row & 7);
  return *(const half8*)(lds + row * 64 + slot * 8);
}
// 256-wide LDS rows (Us in the 256-panel solve): slot = chunk ^ (row&31).
// 16 consecutive-row lanes -> 16 distinct slots -> 2-way aliasing (free).
__device__ __forceinline__ half8 frag256(const half_t* lds, int row, int chunk) {
  int slot = chunk ^ (row & 31);
  return *(const half8*)(lds + row * 256 + slot * 8);
}

// ---------------------------------------------------------------------------
// 1. Row-normalize U -> Vh (fp16). One block per row.
// ---------------------------------------------------------------------------
__global__ __launch_bounds__(256) void normalize_rows(const float* __restrict__ U,
                                                      half_t* __restrict__ Vh) {
  int r = blockIdx.x, t = threadIdx.x;
  float v[7];
  float s = 0.f;
#pragma unroll
  for (int i = 0; i < 7; ++i) {
    v[i] = U[(size_t)r * D_DIM + t + i * 256];
    s += v[i] * v[i];
  }
#pragma unroll
  for (int m = 32; m; m >>= 1) s += __shfl_xor(s, m);
  __shared__ float red[4];
  __shared__ float tot;
  if ((t & 63) == 0) red[t >> 6] = s;
  __syncthreads();
  if (t == 0) tot = 1.0f / sqrtf(red[0] + red[1] + red[2] + red[3]);
  __syncthreads();
  float rn = tot;
#pragma unroll
  for (int i = 0; i < 7; ++i)
    Vh[(size_t)r * D_DIM + t + i * 256] = (half_t)(v[i] * rn);
}

// ---------------------------------------------------------------------------
// 2. Transpose X (fp32, D x B) -> XT (fp16, B x D). 64x64 LDS tiles.
// ---------------------------------------------------------------------------
__global__ __launch_bounds__(256) void transpose_x(const float* __restrict__ X,
                                                   half_t* __restrict__ XT) {
  __shared__ half_t t[64][68];
  int r0 = blockIdx.x * 64, c0 = blockIdx.y * 64;
  int tid = threadIdx.x;
#pragma unroll
  for (int i = 0; i < 16; ++i) {
    int f = tid + i * 256;
    int rr = f >> 6, cc = f & 63;
    t[rr][cc] = (half_t)X[(size_t)(r0 + rr) * B_DIM + c0 + cc];
  }
  __syncthreads();
#pragma unroll
  for (int i = 0; i < 16; ++i) {
    int f = tid + i * 256;
    int cc = f >> 6, rr = f & 63;
    XT[(size_t)(c0 + cc) * D_DIM + r0 + rr] = t[rr][cc];
  }
}

// ---------------------------------------------------------------------------
// 2b. Transpose Vh (fp16, D x D) -> VhT.
// ---------------------------------------------------------------------------
__global__ __launch_bounds__(256) void transpose_h(const half_t* __restrict__ Vh,
                                                   half_t* __restrict__ VhT) {
  __shared__ half_t t[64][68];
  int r0 = blockIdx.x * 64, c0 = blockIdx.y * 64;
  int tid = threadIdx.x;
#pragma unroll
  for (int i = 0; i < 16; ++i) {
    int f = tid + i * 256;
    int rr = f >> 6, cc = f & 63;
    t[rr][cc] = Vh[(size_t)(r0 + rr) * D_DIM + c0 + cc];
  }
  __syncthreads();
#pragma unroll
  for (int i = 0; i < 16; ++i) {
    int f = tid + i * 256;
    int cc = f >> 6, rr = f & 63;
    VhT[(size_t)(c0 + cc) * D_DIM + r0 + rr] = t[rr][cc];
  }
}

// ---------------------------------------------------------------------------
// 3. Big NT MFMA GEMM: 128x128 tile, 2-PHASE pipeline (R7-verified: counted
//    vmcnt(4), static double buffers, next-tile loads in flight over compute).
//    MODE 0 (gram->T16): triangular block skip; Ch = (c<r) ? 2*acc : 0  (fp16)
//    MODE 1 (Pf build):  Ch = (r==c ? 1 : 0) - acc                      (fp16)
//    MODE 2 (final):     Cf = acc (fp32), XCD-swizzled blockIdx (896=8*112)
// ---------------------------------------------------------------------------
template <int MODE>
__global__ __launch_bounds__(256) void gemm_nt(const half_t* __restrict__ A,
                                               const half_t* __restrict__ B,
                                               float* __restrict__ Cf, half_t* __restrict__ Ch,
                                               int K, int lda, int ldb, int ldc) {
  int bx = blockIdx.x, by = blockIdx.y;
  if constexpr (MODE == 2) {
    // T1 XCD swizzle: 896 workgroups, 8 XCDs, 112/XCD (bijective).
    int id = bx + gridDim.x * by;
    int t = (id & 7) * 112 + (id >> 3);
    bx = t % gridDim.x;
    by = t / gridDim.x;
  }
  int m0 = by * 128, n0 = bx * 128;
  if constexpr (MODE == 0) { if (n0 > m0) return; }   // gram: lower+diag blocks only
  __shared__ half_t sA0[128 * 32], sB0[128 * 32];
  __shared__ half_t sA1[128 * 32], sB1[128 * 32];
  int tid = threadIdx.x, lane = tid & 63, wave = tid >> 6;
  int ln15 = lane & 15, quad = lane >> 4;
  int wr = (wave & 1) * 64, wc = (wave >> 1) * 64;
  float4v acc[4][4] = {};
  int KB = K / 32;                     // always even here
  auto compute = [&](const half_t* cA, const half_t* cB) {
    half8 af[4], bf[4];
#pragma unroll
    for (int i = 0; i < 4; ++i) af[i] = frag32(cA, wr + i * 16 + ln15, quad);
#pragma unroll
    for (int j = 0; j < 4; ++j) bf[j] = frag32(cB, wc + j * 16 + ln15, quad);
#pragma unroll
    for (int i = 0; i < 4; ++i)
#pragma unroll
      for (int j = 0; j < 4; ++j)
        acc[i][j] = __builtin_amdgcn_mfma_f32_16x16x32_f16(af[i], bf[j], acc[i][j], 0, 0, 0);
  };
  // prologue: stage tile 0 into buffer pair 0 (4 loads/thread)
  stage_rows(A, m0, lda, 0, sA0, 512, tid);
  stage_rows(B, n0, ldb, 0, sB0, 512, tid);
  for (int kb = 0; kb < KB; kb += 2) {
    stage_rows(A, m0, lda, (kb + 1) * 32, sA1, 512, tid);
    stage_rows(B, n0, ldb, (kb + 1) * 32, sB1, 512, tid);
    asm volatile("s_waitcnt vmcnt(4)" ::: "memory");
    __builtin_amdgcn_s_barrier();
    __builtin_amdgcn_sched_barrier(0);
    compute(sA0, sB0);
    __builtin_amdgcn_sched_barrier(0);
    __builtin_amdgcn_s_barrier();        // pair-0 reads done -> reusable
    if (kb + 2 < KB) {
      stage_rows(A, m0, lda, (kb + 2) * 32, sA0, 512, tid);
      stage_rows(B, n0, ldb, (kb + 2) * 32, sB0, 512, tid);
      asm volatile("s_waitcnt vmcnt(4)" ::: "memory");
    } else {
      asm volatile("s_waitcnt vmcnt(0)" ::: "memory");
    }
    __builtin_amdgcn_s_barrier();
    __builtin_amdgcn_sched_barrier(0);
    compute(sA1, sB1);
    __builtin_amdgcn_sched_barrier(0);
    __builtin_amdgcn_s_barrier();        // pair-1 reads done -> reusable
  }
#pragma unroll
  for (int i = 0; i < 4; ++i)
#pragma unroll
    for (int j = 0; j < 4; ++j)
#pragma unroll
      for (int rg = 0; rg < 4; ++rg) {
        int row = m0 + wr + i * 16 + quad * 4 + rg;
        int col = n0 + wc + j * 16 + ln15;
        size_t idx = (size_t)row * ldc + col;
        float v = acc[i][j][rg];
        if constexpr (MODE == 0) Ch[idx] = (col < row) ? (half_t)(2.0f * v) : (half_t)0.0f;
        else if constexpr (MODE == 1) Ch[idx] = (half_t)(((row == col) ? 1.0f : 0.0f) - v);
        else Cf[idx] = v;
      }
}

// ---------------------------------------------------------------------------
// 4. Invert 14 diagonal 128x128 unit-lower-triangular blocks of T (from T16).
//    One wave per column; forward substitution. -> Dinv (fp16, 14x128x128)
// ---------------------------------------------------------------------------
__global__ __launch_bounds__(256) void diag_inv(const half_t* __restrict__ T16,
                                                half_t* __restrict__ Dinv) {
  int b = blockIdx.x >> 5;        // block 0..13
  int cg = blockIdx.x & 31;       // column group
  int wave = threadIdx.x >> 6, ln = threadIdx.x & 63;
  int c = cg * 4 + wave;          // this wave's column (0..127)
  __shared__ float Ls[128][128];
  __shared__ float xw[4][128];
  for (int i = 0; i < 64; ++i) {
    int f = threadIdx.x + i * 256;
    int r = f >> 7, cc = f & 127;
    Ls[r][cc] = (cc < r) ? (float)T16[(size_t)(b * 128 + r) * D_DIM + b * 128 + cc] : 0.0f;
  }
  __syncthreads();
  float xlo = (ln == 0) ? 1.f : 0.f, xhi = 0.f;
  for (int r = c + 1; r < 128; ++r) {
    float ta = 0.f;
    int j0 = c + ln, j1 = c + 64 + ln;
    if (j0 < r) ta += Ls[r][j0] * xlo;
    if (j1 < r) ta += Ls[r][j1] * xhi;
#pragma unroll
    for (int m = 32; m; m >>= 1) ta += __shfl_xor(ta, m);
    float xr = -ta;
    if (j0 == r) xlo = xr;
    if (j1 == r) xhi = xr;
    if (ln == 0) xw[wave][r] = xr;
  }
  __syncthreads();
  for (int rr = ln; rr < 128; rr += 64) {
    float val = (rr < c) ? 0.f : ((rr == c) ? 1.f : xw[wave][rr]);
    Dinv[(size_t)b * 16384 + (size_t)rr * 128 + c] = (half_t)val;
  }
}

// ---------------------------------------------------------------------------
// 4b. One doubling level: build the 7 diagonal 256x256 inverses from Dinv.
//     D2[b] = [[A^-1, 0], [-B^-1 C A^-1, B^-1]], A=T[2b], B=T[2b+1],
//     C = T16 block (2b+1, 2b). GEMM1: MT = A^-T C^T (NT form), GEMM2:
//     Off = -B^-1 M (NT with MT). One block per pair; all-LDS 128^3 GEMMs.
// ---------------------------------------------------------------------------
__global__ __launch_bounds__(256) void inv256(const half_t* __restrict__ T16,
                                              const half_t* __restrict__ Dinv,
                                              half_t* __restrict__ D2) {
  int b = blockIdx.x;
  __shared__ half_t At[128][136];   // A^-T
  __shared__ half_t Cs[128][136];   // C
  __shared__ half_t Bs[128][136];   // B^-1
  __shared__ half_t Ms[128][136];   // MT = (C·A^-1)^T
  int tid = threadIdx.x, lane = tid & 63, wave = tid >> 6;
  int ln15 = lane & 15, quad = lane >> 4;
  const half_t* A0 = Dinv + (size_t)(2 * b) * 16384;
  const half_t* B0 = Dinv + (size_t)(2 * b + 1) * 16384;
  half_t* Db = D2 + (size_t)b * 65536;
  // quadrant copies (independent of the GEMMs)
  for (int it = 0; it < 64; ++it) {
    int f = tid + it * 256;
    int r = f >> 7, s = f & 127;
    Db[r * 256 + s] = A0[r * 128 + s];
    Db[r * 256 + 128 + s] = (half_t)0.f;
    Db[(128 + r) * 256 + 128 + s] = B0[r * 128 + s];
  }
  // LDS loads
  for (int it = 0; it < 64; ++it) {
    int f = tid + it * 256;
    int k = f >> 7, j = f & 127;
    At[j][k] = A0[k * 128 + j];                     // transpose of A^-1
  }
  for (int it = 0; it < 64; ++it) {
    int f = tid + it * 256;
    int i = f >> 7, k = f & 127;
    Cs[i][k] = T16[(size_t)((2 * b + 1) * 128 + i) * D_DIM + 2 * b * 128 + k];
    Bs[i][k] = B0[i * 128 + k];
  }
  __syncthreads();
  int wr = (wave & 1) * 64, wc = (wave >> 1) * 64;
  // GEMM1 (NT): MT[j][i] = sum_k At[j][k] * Cs[i][k]
  float4v m1[4][4] = {};
#pragma unroll
  for (int kk = 0; kk < 4; ++kk) {
    half8 af[4], bf[4];
#pragma unroll
    for (int i = 0; i < 4; ++i) af[i] = *(const half8*)&At[wr + i * 16 + ln15][kk * 32 + quad * 8];
#pragma unroll
    for (int j = 0; j < 4; ++j) bf[j] = *(const half8*)&Cs[wc + j * 16 + ln15][kk * 32 + quad * 8];
#pragma unroll
    for (int i = 0; i < 4; ++i)
#pragma unroll
      for (int j = 0; j < 4; ++j)
        m1[i][j] = __builtin_amdgcn_mfma_f32_16x16x32_f16(af[i], bf[j], m1[i][j], 0, 0, 0);
  }
#pragma unroll
  for (int i = 0; i < 4; ++i)
#pragma unroll
    for (int j = 0; j < 4; ++j)
#pragma unroll
      for (int rg = 0; rg < 4; ++rg)
        Ms[wr + i * 16 + quad * 4 + rg][wc + j * 16 + ln15] = (half_t)m1[i][j][rg];
  __syncthreads();
  // GEMM2 (NT): Off[i][j] = -sum_k Bs[i][k] * Ms[j][k]
  float4v o2[4][4] = {};
#pragma unroll
  for (int kk = 0; kk < 4; ++kk) {
    half8 af[4], bf[4];
#pragma unroll
    for (int i = 0; i < 4; ++i) af[i] = *(const half8*)&Bs[wr + i * 16 + ln15][kk * 32 + quad * 8];
#pragma unroll
    for (int j = 0; j < 4; ++j) bf[j] = *(const half8*)&Ms[wc + j * 16 + ln15][kk * 32 + quad * 8];
#pragma unroll
    for (int i = 0; i < 4; ++i)
#pragma unroll
      for (int j = 0; j < 4; ++j)
        o2[i][j] = __builtin_amdgcn_mfma_f32_16x16x32_f16(af[i], bf[j], o2[i][j], 0, 0, 0);
  }
#pragma unroll
  for (int i = 0; i < 4; ++i)
#pragma unroll
    for (int j = 0; j < 4; ++j)
#pragma unroll
      for (int rg = 0; rg < 4; ++rg)
        Db[(size_t)(128 + wr + i * 16 + quad * 4 + rg) * 256 + wc + j * 16 + ln15] =
            (half_t)(-o2[i][j][rg]);
}

// ---------------------------------------------------------------------------
// 5. FUSED blocked forward substitution — 256-WIDE PANELS (R8).
//    7 serial panels (was 14): K-rounds 182->84, staged bytes -23%, panel
//    overhead halved. K-loop keeps the R3-proven depth-3 coop-DMA ring
//    (PDIST=2, counted vmcnt 20/10/0). Phase 4 multiplies by the 256-block
//    inverse D2 read DIRECTLY from global (L2-resident one-shot burst; no
//    LDS-DMA, no serial chain). LDS = ring 120KB + Us 32KB = 152KB static.
//    Per panel ib (K = ib*256):
//      Ut[m][s] = 2*Vn[ib*256+s][m] - sum_{k<ib*256} WtT[m][k]*T16[ib*256+s][k]
//      WtT[m][ib*256+r] = sum_s Ut[m][s]*D2[ib][r][s]
// ---------------------------------------------------------------------------
#define NBUF 3
#define PDIST 2
// per-buffer (halves): A 64x64 = 4096, B 256x64 = 16384 -> 20480 (40KB)
#define BUF_HALVES 20480

__global__ __launch_bounds__(256, 1) void fused_solve(const half_t* __restrict__ T16,
                                                      const half_t* __restrict__ VhT,
                                                      const half_t* __restrict__ D2,
                                                      half_t* __restrict__ WtT) {
  __shared__ half_t ring[NBUF * BUF_HALVES];   // 120KB staging ring
  __shared__ half_t Us[64 * 256];              // 32KB (phase 2 -> 4)
  int tid = threadIdx.x, lane = tid & 63, wave = tid >> 6;
  int ln15 = lane & 15, quad = lane >> 4;
  int m0 = blockIdx.x * 64;
  int wr = (wave & 1) * 32;          // m-offset of this wave (0/32)
  int wcK = (wave >> 1) * 128;       // n-offset over the 256 panel cols (0/128)
  for (int ib = 0; ib < 7; ++ib) {
    // drain prev panel's WtT stores (vmcnt0) + phase-4 Us reads; frees ring/Us
    __syncthreads();
    // hoisted per-panel VhT loads (K-loop-independent; hide under it)
    float vnf[2][8][4];
#pragma unroll
    for (int i = 0; i < 2; ++i)
#pragma unroll
      for (int j = 0; j < 8; ++j)
#pragma unroll
        for (int rg = 0; rg < 4; ++rg)
          vnf[i][j][rg] = (float)VhT[(size_t)(m0 + wr + i * 16 + quad * 4 + rg) * D_DIM
                                     + ib * 256 + wcK + j * 16 + ln15];
    __builtin_amdgcn_sched_barrier(0);   // keep hoisted loads above the K-loop
    float4v acc[2][8] = {};
    int Ksteps = ib * 4;               // BK=64 steps over K = ib*256
    if (Ksteps > 0) {
      int npre = Ksteps < PDIST ? Ksteps : PDIST;
      for (int p = 0; p < npre; ++p) {
        half_t* bA = ring + p * BUF_HALVES;
        half_t* bB = bA + 4096;
        stage_rows64(WtT, m0, D_DIM, p * 64, bA, 512, tid);
        stage_rows64(T16, ib * 256, D_DIM, p * 64, bB, 2048, tid);
      }
      for (int kb = 0; kb < Ksteps; ++kb) {
        if (kb + PDIST < Ksteps) {
          int slot = (kb + PDIST) % NBUF, k0 = (kb + PDIST) * 64;
          half_t* bA = ring + slot * BUF_HALVES;
          half_t* bB = bA + 4096;
          stage_rows64(WtT, m0, D_DIM, k0, bA, 512, tid);
          stage_rows64(T16, ib * 256, D_DIM, k0, bB, 2048, tid);
        }
        // 10 DMA/thread per staged buffer; buffers ahead = min(R, PDIST)
        int R = Ksteps - 1 - kb;
        if (R >= 2)      asm volatile("s_waitcnt vmcnt(20)" ::: "memory");
        else if (R == 1) asm volatile("s_waitcnt vmcnt(10)" ::: "memory");
        else             asm volatile("s_waitcnt vmcnt(0)"  ::: "memory");
        __builtin_amdgcn_s_barrier();        // all waves' buf[kb] loads landed
        __builtin_amdgcn_sched_barrier(0);   // pin ds_reads below the barrier
        half_t* cA = ring + (kb % NBUF) * BUF_HALVES;
        half_t* cB = cA + 4096;
        half8 af[2], bf[8];
#pragma unroll
        for (int q = 0; q < 2; ++q) {
#pragma unroll
          for (int i = 0; i < 2; ++i) af[i] = frag64(cA, wr + i * 16 + ln15, q * 4 + quad);
#pragma unroll
          for (int j = 0; j < 8; ++j) bf[j] = frag64(cB, wcK + j * 16 + ln15, q * 4 + quad);
#pragma unroll
          for (int i = 0; i < 2; ++i)
#pragma unroll
            for (int j = 0; j < 8; ++j)
              acc[i][j] = __builtin_amdgcn_mfma_f32_16x16x32_f16(af[i], bf[j], acc[i][j], 0, 0, 0);
        }
        __builtin_amdgcn_sched_barrier(0);   // pin ds_reads above the barrier
        __builtin_amdgcn_s_barrier();        // buf[kb] now safe to overwrite
      }
    }
    // phase 2: Ut = 2*VnT - acc  -> Us (A-operand layout, 256-swizzled)
#pragma unroll
    for (int i = 0; i < 2; ++i)
#pragma unroll
      for (int j = 0; j < 8; ++j)
#pragma unroll
        for (int rg = 0; rg < 4; ++rg) {
          int rl = wr + i * 16 + quad * 4 + rg;     // local m (0..63)
          int cl = wcK + j * 16 + ln15;             // local s (0..255)
          float u = 2.f * vnf[i][j][rg] - acc[i][j][rg];
          int sc = cl >> 3;
          Us[rl * 256 + ((sc ^ (rl & 31)) << 3) + (cl & 7)] = (half_t)u;
        }
    __syncthreads();   // Us ds_writes visible to all waves
    // phase 4: WtT-panel(64x256) = Ut * D2[ib]^T (K=256). B-fragments read
    // directly from global (L2-resident; independent burst, not a chain).
    {
      int wcR = (wave >> 1) * 128;     // r-offset (0/128)
      const half_t* Db = D2 + (size_t)ib * 65536;
      float4v a2[2][8] = {};
#pragma unroll
      for (int kk = 0; kk < 8; ++kk) {
        half8 af[2], bf[8];
#pragma unroll
        for (int i = 0; i < 2; ++i) af[i] = frag256(Us, wr + i * 16 + ln15, kk * 4 + quad);
#pragma unroll
        for (int j = 0; j < 8; ++j)
          bf[j] = *(const half8*)(Db + (size_t)(wcR + j * 16 + ln15) * 256 + kk * 32 + quad * 8);
#pragma unroll
        for (int i = 0; i < 2; ++i)
#pragma unroll
          for (int j = 0; j < 8; ++j)
            a2[i][j] = __builtin_amdgcn_mfma_f32_16x16x32_f16(af[i], bf[j], a2[i][j], 0, 0, 0);
      }
#pragma unroll
      for (int i = 0; i < 2; ++i)
#pragma unroll
        for (int j = 0; j < 8; ++j)
#pragma unroll
          for (int rg = 0; rg < 4; ++rg) {
            int rl = wr + i * 16 + quad * 4 + rg;
            int cl = wcR + j * 16 + ln15;
            WtT[(size_t)(m0 + rl) * D_DIM + ib * 256 + cl] = (half_t)a2[i][j][rg];
          }
    }
  }
}

// ---------------------------------------------------------------------------
extern "C" void kernel_launch(void* const* d_in, const int* in_sizes, int n_in,
                              void* d_out, int out_size, void* d_ws, size_t ws_size,
                              hipStream_t stream) {
  (void)in_sizes; (void)n_in; (void)out_size; (void)ws_size;
  const float* X = (const float*)d_in[0];   // (1792, 8192) fp32
  const float* U = (const float*)d_in[1];   // (1792, 1792) fp32
  float* out = (float*)d_out;               // (1792, 8192) fp32

  char* ws = (char*)d_ws;
  half_t* XT   = (half_t*)(ws);                    // 29,360,128 B
  half_t* Vh   = (half_t*)(ws + 29360128);         //  6,422,528 B
  half_t* VhT  = (half_t*)(ws + 35782656);         //  6,422,528 B
  half_t* T16  = (half_t*)(ws + 42205184);         //  6,422,528 B
  half_t* WtT  = (half_t*)(ws + 48627712);         //  6,422,528 B
  half_t* Dinv = (half_t*)(ws + 55050240);         //    458,752 B
  half_t* Pf   = (half_t*)(ws + 55508992);         //  6,422,528 B
  half_t* D2   = (half_t*)(ws + 61931520);         //    917,504 B (total ~63 MB)

  normalize_rows<<<dim3(D_DIM), dim3(256), 0, stream>>>(U, Vh);
  transpose_x<<<dim3(D_DIM / 64, B_DIM / 64), dim3(256), 0, stream>>>(X, XT);
  // T16 = 2*strict_tril(Vn Vn^T) directly (gram fused with build_T16)
  gemm_nt<0><<<dim3(14, 14), dim3(256), 0, stream>>>(Vh, Vh, nullptr, T16,
                                                     D_DIM, D_DIM, D_DIM, D_DIM);
  transpose_h<<<dim3(28, 28), dim3(256), 0, stream>>>(Vh, VhT);
  diag_inv<<<dim3(448), dim3(256), 0, stream>>>(T16, Dinv);
  // doubling level: 7 x 256 diagonal-block inverses
  inv256<<<dim3(7), dim3(256), 0, stream>>>(T16, Dinv, D2);
  // one-launch blocked forward substitution, 256-wide panels
  fused_solve<<<dim3(28), dim3(256), 0, stream>>>(T16, VhT, D2, WtT);
  // Pf = I - Wt^T Vn
  gemm_nt<1><<<dim3(14, 14), dim3(256), 0, stream>>>(WtT, VhT, nullptr, Pf,
                                                     D_DIM, D_DIM, D_DIM, D_DIM);
  // out = Pf X
  gemm_nt<2><<<dim3(64, 14), dim3(256), 0, stream>>>(Pf, XT, out, nullptr,
                                                     D_DIM, D_DIM, D_DIM, B_DIM);
}

// Round 10
// 463.600 us; speedup vs baseline: 1.0648x; 1.0648x over previous
//
#include <hip/hip_runtime.h>
#include <stdint.h>
#include <stddef.h>

typedef _Float16 half_t;
typedef _Float16 half8 __attribute__((ext_vector_type(8)));
typedef float float4v __attribute__((ext_vector_type(4)));

#define D_DIM 1792
#define B_DIM 8192

// ---------------------------------------------------------------------------
// Async global->LDS staging of ROWS*32 fp16 tile (rows along K, NT layout).
// slot = chunk ^ ((row>>1)&3): conflict-free (verified SQ_LDS_BANK_CONFLICT=0).
// ---------------------------------------------------------------------------
__device__ __forceinline__ void stage_rows(const half_t* __restrict__ src, int row0, int ld,
                                           int k0, half_t* dst, int nchunks, int tid) {
  for (int base = 0; base < nchunks; base += 256) {
    int ch  = base + tid;
    int row = ch >> 2, kc = ch & 3;
    int swz = kc ^ ((row >> 1) & 3);
    const half_t* g = src + (size_t)(row0 + row) * ld + k0 + swz * 8;
    half_t* l = dst + (size_t)(base + (tid & 192)) * 8;   // wave-uniform base; HW adds lane*16B
    __builtin_amdgcn_global_load_lds(
        (const __attribute__((address_space(1))) uint32_t*)(const void*)g,
        (__attribute__((address_space(3))) uint32_t*)(void*)l, 16, 0, 0);
  }
}

__device__ __forceinline__ half8 frag32(const half_t* lds, int row, int chunk) {
  int slot = chunk ^ ((row >> 1) & 3);
  return *(const half8*)(lds + row * 32 + slot * 8);
}

// ---------------------------------------------------------------------------
// 1. Row-normalize U -> Vh (fp16). One block per row.
// ---------------------------------------------------------------------------
__global__ __launch_bounds__(256) void normalize_rows(const float* __restrict__ U,
                                                      half_t* __restrict__ Vh) {
  int r = blockIdx.x, t = threadIdx.x;
  float v[7];
  float s = 0.f;
#pragma unroll
  for (int i = 0; i < 7; ++i) {
    v[i] = U[(size_t)r * D_DIM + t + i * 256];
    s += v[i] * v[i];
  }
#pragma unroll
  for (int m = 32; m; m >>= 1) s += __shfl_xor(s, m);
  __shared__ float red[4];
  __shared__ float tot;
  if ((t & 63) == 0) red[t >> 6] = s;
  __syncthreads();
  if (t == 0) tot = 1.0f / sqrtf(red[0] + red[1] + red[2] + red[3]);
  __syncthreads();
  float rn = tot;
#pragma unroll
  for (int i = 0; i < 7; ++i)
    Vh[(size_t)r * D_DIM + t + i * 256] = (half_t)(v[i] * rn);
}

// ---------------------------------------------------------------------------
// 2. Transpose X (fp32, D x B) -> XT (fp16, B x D). 64x64 LDS tiles.
//    NOTE: launched AFTER the WtT GEMM — XT's first 6.4MB aliases Tinv.
// ---------------------------------------------------------------------------
__global__ __launch_bounds__(256) void transpose_x(const float* __restrict__ X,
                                                   half_t* __restrict__ XT) {
  __shared__ half_t t[64][68];
  int r0 = blockIdx.x * 64, c0 = blockIdx.y * 64;
  int tid = threadIdx.x;
#pragma unroll
  for (int i = 0; i < 16; ++i) {
    int f = tid + i * 256;
    int rr = f >> 6, cc = f & 63;
    t[rr][cc] = (half_t)X[(size_t)(r0 + rr) * B_DIM + c0 + cc];
  }
  __syncthreads();
#pragma unroll
  for (int i = 0; i < 16; ++i) {
    int f = tid + i * 256;
    int cc = f >> 6, rr = f & 63;
    XT[(size_t)(c0 + cc) * D_DIM + r0 + rr] = t[rr][cc];
  }
}

// ---------------------------------------------------------------------------
// 2b. Transpose Vh (fp16, D x D) -> VhT.
// ---------------------------------------------------------------------------
__global__ __launch_bounds__(256) void transpose_h(const half_t* __restrict__ Vh,
                                                   half_t* __restrict__ VhT) {
  __shared__ half_t t[64][68];
  int r0 = blockIdx.x * 64, c0 = blockIdx.y * 64;
  int tid = threadIdx.x;
#pragma unroll
  for (int i = 0; i < 16; ++i) {
    int f = tid + i * 256;
    int rr = f >> 6, cc = f & 63;
    t[rr][cc] = Vh[(size_t)(r0 + rr) * D_DIM + c0 + cc];
  }
  __syncthreads();
#pragma unroll
  for (int i = 0; i < 16; ++i) {
    int f = tid + i * 256;
    int cc = f >> 6, rr = f & 63;
    VhT[(size_t)(c0 + cc) * D_DIM + r0 + rr] = t[rr][cc];
  }
}

// ---------------------------------------------------------------------------
// 2c. Zero the block-level zero triangles (R10 FIX — R9's absmax 29.9 was
//     uninitialized reads here): Tinv strict-UPPER 128-blocks and TinvT
//     strict-LOWER 128-blocks are read as dense operands by the doubling
//     GEMMs but were never written. ~5.8MB of stores, ~2us.
// ---------------------------------------------------------------------------
__global__ __launch_bounds__(256) void zero_tri(half_t* __restrict__ Tinv,
                                                half_t* __restrict__ TinvT) {
  int bc = blockIdx.x, br = blockIdx.y;
  int tid = threadIdx.x;
  half8 z = {};
  if (bc > br) {
    for (int it = 0; it < 8; ++it) {
      int ch = it * 256 + tid;
      int r = ch >> 4, c = (ch & 15) * 8;
      *(half8*)(Tinv + (size_t)(br * 128 + r) * D_DIM + bc * 128 + c) = z;
    }
  } else if (bc < br) {
    for (int it = 0; it < 8; ++it) {
      int ch = it * 256 + tid;
      int r = ch >> 4, c = (ch & 15) * 8;
      *(half8*)(TinvT + (size_t)(br * 128 + r) * D_DIM + bc * 128 + c) = z;
    }
  }
}

// ---------------------------------------------------------------------------
// 3. Big NT MFMA GEMM: 128x128 tile, 2-PHASE pipeline (R7-verified: counted
//    vmcnt(4), static double buffers, next-tile loads in flight over compute).
//    MODE 0 (gram->T16): triangular block skip; Ch = (c<r) ? 2*acc : 0  (fp16)
//    MODE 1 (Pf build):  Ch = (r==c ? 1 : 0) - acc                      (fp16)
//    MODE 2 (final):     Cf = acc (fp32), XCD-swizzled blockIdx (896=8*112)
//    MODE 3 (WtT):       Ch = 2*acc; per-block K = n0+128 (triangular Tinv)
// ---------------------------------------------------------------------------
template <int MODE>
__global__ __launch_bounds__(256) void gemm_nt(const half_t* __restrict__ A,
                                               const half_t* __restrict__ B,
                                               float* __restrict__ Cf, half_t* __restrict__ Ch,
                                               int K, int lda, int ldb, int ldc) {
  int bx = blockIdx.x, by = blockIdx.y;
  if constexpr (MODE == 2) {
    // T1 XCD swizzle: 896 workgroups, 8 XCDs, 112/XCD (bijective).
    int id = bx + gridDim.x * by;
    int t = (id & 7) * 112 + (id >> 3);
    bx = t % gridDim.x;
    by = t / gridDim.x;
  }
  int m0 = by * 128, n0 = bx * 128;
  if constexpr (MODE == 0) { if (n0 > m0) return; }   // gram: lower+diag blocks only
  int Keff = K;
  if constexpr (MODE == 3) Keff = n0 + 128;           // Tinv rows r: k <= r only
  __shared__ half_t sA0[128 * 32], sB0[128 * 32];
  __shared__ half_t sA1[128 * 32], sB1[128 * 32];
  int tid = threadIdx.x, lane = tid & 63, wave = tid >> 6;
  int ln15 = lane & 15, quad = lane >> 4;
  int wr = (wave & 1) * 64, wc = (wave >> 1) * 64;
  float4v acc[4][4] = {};
  int KB = Keff / 32;                  // always even here (multiples of 4)
  auto compute = [&](const half_t* cA, const half_t* cB) {
    half8 af[4], bf[4];
#pragma unroll
    for (int i = 0; i < 4; ++i) af[i] = frag32(cA, wr + i * 16 + ln15, quad);
#pragma unroll
    for (int j = 0; j < 4; ++j) bf[j] = frag32(cB, wc + j * 16 + ln15, quad);
#pragma unroll
    for (int i = 0; i < 4; ++i)
#pragma unroll
      for (int j = 0; j < 4; ++j)
        acc[i][j] = __builtin_amdgcn_mfma_f32_16x16x32_f16(af[i], bf[j], acc[i][j], 0, 0, 0);
  };
  // prologue: stage tile 0 into buffer pair 0 (4 loads/thread)
  stage_rows(A, m0, lda, 0, sA0, 512, tid);
  stage_rows(B, n0, ldb, 0, sB0, 512, tid);
  for (int kb = 0; kb < KB; kb += 2) {
    stage_rows(A, m0, lda, (kb + 1) * 32, sA1, 512, tid);
    stage_rows(B, n0, ldb, (kb + 1) * 32, sB1, 512, tid);
    asm volatile("s_waitcnt vmcnt(4)" ::: "memory");
    __builtin_amdgcn_s_barrier();
    __builtin_amdgcn_sched_barrier(0);
    compute(sA0, sB0);
    __builtin_amdgcn_sched_barrier(0);
    __builtin_amdgcn_s_barrier();        // pair-0 reads done -> reusable
    if (kb + 2 < KB) {
      stage_rows(A, m0, lda, (kb + 2) * 32, sA0, 512, tid);
      stage_rows(B, n0, ldb, (kb + 2) * 32, sB0, 512, tid);
      asm volatile("s_waitcnt vmcnt(4)" ::: "memory");
    } else {
      asm volatile("s_waitcnt vmcnt(0)" ::: "memory");
    }
    __builtin_amdgcn_s_barrier();
    __builtin_amdgcn_sched_barrier(0);
    compute(sA1, sB1);
    __builtin_amdgcn_sched_barrier(0);
    __builtin_amdgcn_s_barrier();        // pair-1 reads done -> reusable
  }
#pragma unroll
  for (int i = 0; i < 4; ++i)
#pragma unroll
    for (int j = 0; j < 4; ++j)
#pragma unroll
      for (int rg = 0; rg < 4; ++rg) {
        int row = m0 + wr + i * 16 + quad * 4 + rg;
        int col = n0 + wc + j * 16 + ln15;
        size_t idx = (size_t)row * ldc + col;
        float v = acc[i][j][rg];
        if constexpr (MODE == 0) Ch[idx] = (col < row) ? (half_t)(2.0f * v) : (half_t)0.0f;
        else if constexpr (MODE == 1) Ch[idx] = (half_t)(((row == col) ? 1.0f : 0.0f) - v);
        else if constexpr (MODE == 3) Ch[idx] = (half_t)(2.0f * v);
        else Cf[idx] = v;
      }
}

// ---------------------------------------------------------------------------
// 4. Invert 14 diagonal 128x128 unit-lower-triangular blocks of T (from T16).
//    One wave per column; forward substitution. Writes BOTH Tinv and TinvT
//    diagonal blocks (full 128x128 incl. zeros above diag).
// ---------------------------------------------------------------------------
__global__ __launch_bounds__(256) void diag_inv(const half_t* __restrict__ T16,
                                                half_t* __restrict__ Tinv,
                                                half_t* __restrict__ TinvT) {
  int b = blockIdx.x >> 5;        // block 0..13
  int cg = blockIdx.x & 31;       // column group
  int wave = threadIdx.x >> 6, ln = threadIdx.x & 63;
  int c = cg * 4 + wave;          // this wave's column (0..127)
  __shared__ float Ls[128][128];
  __shared__ float xw[4][128];
  for (int i = 0; i < 64; ++i) {
    int f = threadIdx.x + i * 256;
    int r = f >> 7, cc = f & 127;
    Ls[r][cc] = (cc < r) ? (float)T16[(size_t)(b * 128 + r) * D_DIM + b * 128 + cc] : 0.0f;
  }
  __syncthreads();
  float xlo = (ln == 0) ? 1.f : 0.f, xhi = 0.f;
  for (int r = c + 1; r < 128; ++r) {
    float ta = 0.f;
    int j0 = c + ln, j1 = c + 64 + ln;
    if (j0 < r) ta += Ls[r][j0] * xlo;
    if (j1 < r) ta += Ls[r][j1] * xhi;
#pragma unroll
    for (int m = 32; m; m >>= 1) ta += __shfl_xor(ta, m);
    float xr = -ta;
    if (j0 == r) xlo = xr;
    if (j1 == r) xhi = xr;
    if (ln == 0) xw[wave][r] = xr;
  }
  __syncthreads();
  for (int rr = ln; rr < 128; rr += 64) {
    float val = (rr < c) ? 0.f : ((rr == c) ? 1.f : xw[wave][rr]);
    half_t hv = (half_t)val;
    Tinv[(size_t)(b * 128 + rr) * D_DIM + b * 128 + c] = hv;
    TinvT[(size_t)(b * 128 + c) * D_DIM + b * 128 + rr] = hv;
  }
}

// ---------------------------------------------------------------------------
// 5. RECURSIVE DOUBLING of T^-1 (replaces the serial fused_solve — R1..R8
//    showed its K-loop pinned at ~12 B/cy/CU staging floor, 28 CUs, 182
//    serial rounds). Generic batched NT GEMM: R[m][n] = sum_k A[m][k]B[n][k],
//    z = pair index (ptr += z*stride). Optional negate; O1 row-major [m][n],
//    optional O2 transposed [n][m]. 2-phase staging (R7-verified).
//    Per pair (A p x p at Aoff, B q x q at Boff = Aoff+p):
//      M1T[j][i] = sum_k TinvT[Ao+j][Ao+k] * T16[Bo+i][Ao+k]   (= (C invA)^T)
//      M2T[j][i] = sum_k M1T[j][k] * Tinv[Bo+i][Bo+k]          (= (invB M1)^T)
//      Tinv[Bo+i][Ao+j] = TinvT[Ao+j][Bo+i] = -M2T[j][i]
// ---------------------------------------------------------------------------
__global__ __launch_bounds__(256) void tinv_nt(const half_t* __restrict__ A, int ldA, long long strA,
                                               const half_t* __restrict__ B, int ldB, long long strB,
                                               half_t* __restrict__ O1, int ldO1, long long strO1,
                                               half_t* __restrict__ O2, int ldO2, long long strO2,
                                               int K, int neg) {
  long long z = blockIdx.z;
  A += z * strA;
  B += z * strB;
  O1 += z * strO1;
  if (O2) O2 += z * strO2;
  int m0 = blockIdx.y * 128, n0 = blockIdx.x * 128;
  __shared__ half_t sA0[128 * 32], sB0[128 * 32];
  __shared__ half_t sA1[128 * 32], sB1[128 * 32];
  int tid = threadIdx.x, lane = tid & 63, wave = tid >> 6;
  int ln15 = lane & 15, quad = lane >> 4;
  int wr = (wave & 1) * 64, wc = (wave >> 1) * 64;
  float4v acc[4][4] = {};
  int KB = K / 32;                     // K in {128,256,512,768,1024}: KB even
  auto compute = [&](const half_t* cA, const half_t* cB) {
    half8 af[4], bf[4];
#pragma unroll
    for (int i = 0; i < 4; ++i) af[i] = frag32(cA, wr + i * 16 + ln15, quad);
#pragma unroll
    for (int j = 0; j < 4; ++j) bf[j] = frag32(cB, wc + j * 16 + ln15, quad);
#pragma unroll
    for (int i = 0; i < 4; ++i)
#pragma unroll
      for (int j = 0; j < 4; ++j)
        acc[i][j] = __builtin_amdgcn_mfma_f32_16x16x32_f16(af[i], bf[j], acc[i][j], 0, 0, 0);
  };
  stage_rows(A, m0, ldA, 0, sA0, 512, tid);
  stage_rows(B, n0, ldB, 0, sB0, 512, tid);
  for (int kb = 0; kb < KB; kb += 2) {
    stage_rows(A, m0, ldA, (kb + 1) * 32, sA1, 512, tid);
    stage_rows(B, n0, ldB, (kb + 1) * 32, sB1, 512, tid);
    asm volatile("s_waitcnt vmcnt(4)" ::: "memory");
    __builtin_amdgcn_s_barrier();
    __builtin_amdgcn_sched_barrier(0);
    compute(sA0, sB0);
    __builtin_amdgcn_sched_barrier(0);
    __builtin_amdgcn_s_barrier();
    if (kb + 2 < KB) {
      stage_rows(A, m0, ldA, (kb + 2) * 32, sA0, 512, tid);
      stage_rows(B, n0, ldB, (kb + 2) * 32, sB0, 512, tid);
      asm volatile("s_waitcnt vmcnt(4)" ::: "memory");
    } else {
      asm volatile("s_waitcnt vmcnt(0)" ::: "memory");
    }
    __builtin_amdgcn_s_barrier();
    __builtin_amdgcn_sched_barrier(0);
    compute(sA1, sB1);
    __builtin_amdgcn_sched_barrier(0);
    __builtin_amdgcn_s_barrier();
  }
#pragma unroll
  for (int i = 0; i < 4; ++i)
#pragma unroll
    for (int j = 0; j < 4; ++j)
#pragma unroll
      for (int rg = 0; rg < 4; ++rg) {
        int m = m0 + wr + i * 16 + quad * 4 + rg;
        int n = n0 + wc + j * 16 + ln15;
        float v = acc[i][j][rg];
        if (neg) v = -v;
        half_t hv = (half_t)v;
        O1[(size_t)m * ldO1 + n] = hv;
        if (O2) O2[(size_t)n * ldO2 + m] = hv;
      }
}

// ---------------------------------------------------------------------------
extern "C" void kernel_launch(void* const* d_in, const int* in_sizes, int n_in,
                              void* d_out, int out_size, void* d_ws, size_t ws_size,
                              hipStream_t stream) {
  (void)in_sizes; (void)n_in; (void)out_size; (void)ws_size;
  const float* X = (const float*)d_in[0];   // (1792, 8192) fp32
  const float* U = (const float*)d_in[1];   // (1792, 1792) fp32
  float* out = (float*)d_out;               // (1792, 8192) fp32

  char* ws = (char*)d_ws;
  // Slab plan (61.47 MB total, < R8's verified 62.85 MB):
  //   [0 .. 29.36M)  XT  (written LAST by transpose_x); Tinv aliases its
  //                  first 6.42MB during the solve (dead before transpose_x)
  //   [29.36M..35.78M) Vh; reused as M1T scratch after gram+transpose_h
  //   [35.78M..42.21M) VhT
  //   [42.21M..48.63M) T16
  //   [48.63M..55.05M) WtT
  //   [55.05M..61.47M) TinvT; reused as Pf after the WtT GEMM
  half_t* Tinv  = (half_t*)(ws);
  half_t* XT    = (half_t*)(ws);
  half_t* Vh    = (half_t*)(ws + 29360128);
  half_t* scr   = Vh;                       // M1T scratch (<= 1.57MB used)
  half_t* VhT   = (half_t*)(ws + 35782656);
  half_t* T16   = (half_t*)(ws + 42205184);
  half_t* WtT   = (half_t*)(ws + 48627712);
  half_t* TinvT = (half_t*)(ws + 55050240);
  half_t* Pf    = TinvT;

  const int D = D_DIM;

  normalize_rows<<<dim3(D), dim3(256), 0, stream>>>(U, Vh);
  // T16 = 2*strict_tril(Vn Vn^T)
  gemm_nt<0><<<dim3(14, 14), dim3(256), 0, stream>>>(Vh, Vh, nullptr, T16, D, D, D, D);
  transpose_h<<<dim3(28, 28), dim3(256), 0, stream>>>(Vh, VhT);
  // 14 x 128 diagonal-block inverses -> Tinv/TinvT diag blocks
  diag_inv<<<dim3(448), dim3(256), 0, stream>>>(T16, Tinv, TinvT);
  // R10 FIX: zero Tinv strict-upper / TinvT strict-lower blocks (the doubling
  // GEMMs read these as dense operands; R9 left them uninitialized)
  zero_tri<<<dim3(14, 14), dim3(256), 0, stream>>>(Tinv, TinvT);

  // --- recursive doubling: fill strict-lower blocks of Tinv/TinvT ---
  // L1: 7 pairs of 128 (Aoff=256z, Boff=256z+128)
  {
    long long st = 256LL * D + 256;
    tinv_nt<<<dim3(1, 1, 7), dim3(256), 0, stream>>>(
        TinvT, D, st, T16 + 128LL * D, D, st, scr, 128, 16384, nullptr, 0, 0, 128, 0);
    tinv_nt<<<dim3(1, 1, 7), dim3(256), 0, stream>>>(
        scr, 128, 16384, Tinv + 128LL * D + 128, D, st,
        TinvT + 128, D, st, Tinv + 128LL * D, D, st, 128, 1);
  }
  // L2: 3 pairs of 256 (Aoff=512z, Boff=512z+256)
  {
    long long st = 512LL * D + 512;
    tinv_nt<<<dim3(2, 2, 3), dim3(256), 0, stream>>>(
        TinvT, D, st, T16 + 256LL * D, D, st, scr, 256, 65536, nullptr, 0, 0, 256, 0);
    tinv_nt<<<dim3(2, 2, 3), dim3(256), 0, stream>>>(
        scr, 256, 65536, Tinv + 256LL * D + 256, D, st,
        TinvT + 256, D, st, Tinv + 256LL * D, D, st, 256, 1);
  }
  // L3a: pair (512@0, 512@512)
  tinv_nt<<<dim3(4, 4, 1), dim3(256), 0, stream>>>(
      TinvT, D, 0, T16 + 512LL * D, D, 0, scr, 512, 0, nullptr, 0, 0, 512, 0);
  tinv_nt<<<dim3(4, 4, 1), dim3(256), 0, stream>>>(
      scr, 512, 0, Tinv + 512LL * D + 512, D, 0,
      TinvT + 512, D, 0, Tinv + 512LL * D, D, 0, 512, 1);
  // L3b: pair (512@1024, 256@1536): p=512, q=256
  tinv_nt<<<dim3(2, 4, 1), dim3(256), 0, stream>>>(
      TinvT + 1024LL * D + 1024, D, 0, T16 + 1536LL * D + 1024, D, 0,
      scr, 256, 0, nullptr, 0, 0, 512, 0);
  tinv_nt<<<dim3(2, 4, 1), dim3(256), 0, stream>>>(
      scr, 256, 0, Tinv + 1536LL * D + 1536, D, 0,
      TinvT + 1024LL * D + 1536, D, 0, Tinv + 1536LL * D + 1024, D, 0, 256, 1);
  // L4: pair (1024@0, 768@1024): p=1024, q=768
  tinv_nt<<<dim3(6, 8, 1), dim3(256), 0, stream>>>(
      TinvT, D, 0, T16 + 1024LL * D, D, 0, scr, 768, 0, nullptr, 0, 0, 1024, 0);
  tinv_nt<<<dim3(6, 8, 1), dim3(256), 0, stream>>>(
      scr, 768, 0, Tinv + 1024LL * D + 1024, D, 0,
      TinvT + 1024, D, 0, Tinv + 1024LL * D, D, 0, 768, 1);

  // WtT[m][r] = 2 * sum_{k<=r} VhT[m][k] * Tinv[r][k]   (triangular K)
  gemm_nt<3><<<dim3(14, 14), dim3(256), 0, stream>>>(VhT, Tinv, nullptr, WtT, 0, D, D, D);
  // Tinv now dead -> safe to build XT over its slab
  transpose_x<<<dim3(D / 64, B_DIM / 64), dim3(256), 0, stream>>>(X, XT);
  // Pf = I - Wt^T Vn   (Pf overlays dead TinvT)
  gemm_nt<1><<<dim3(14, 14), dim3(256), 0, stream>>>(WtT, VhT, nullptr, Pf, D, D, D, D);
  // out = Pf X
  gemm_nt<2><<<dim3(64, 14), dim3(256), 0, stream>>>(Pf, XT, out, nullptr, D, D, D, B_DIM);
}

// Round 11
// 396.690 us; speedup vs baseline: 1.2444x; 1.1687x over previous
//
#include <hip/hip_runtime.h>
#include <stdint.h>
#include <stddef.h>

typedef _Float16 half_t;
typedef _Float16 half8 __attribute__((ext_vector_type(8)));
typedef float float4v __attribute__((ext_vector_type(4)));

#define D_DIM 1792
#define B_DIM 8192

// ---------------------------------------------------------------------------
// Async global->LDS staging of ROWS*32 fp16 tile (rows along K, NT layout).
// slot = chunk ^ ((row>>1)&3): conflict-free (verified SQ_LDS_BANK_CONFLICT=0).
// ---------------------------------------------------------------------------
__device__ __forceinline__ void stage_rows(const half_t* __restrict__ src, int row0, int ld,
                                           int k0, half_t* dst, int nchunks, int tid) {
  for (int base = 0; base < nchunks; base += 256) {
    int ch  = base + tid;
    int row = ch >> 2, kc = ch & 3;
    int swz = kc ^ ((row >> 1) & 3);
    const half_t* g = src + (size_t)(row0 + row) * ld + k0 + swz * 8;
    half_t* l = dst + (size_t)(base + (tid & 192)) * 8;   // wave-uniform base; HW adds lane*16B
    __builtin_amdgcn_global_load_lds(
        (const __attribute__((address_space(1))) uint32_t*)(const void*)g,
        (__attribute__((address_space(3))) uint32_t*)(void*)l, 16, 0, 0);
  }
}

// FULL-LINE staging (128B/row = one aligned L2 line). slot = kc ^ (row&7).
__device__ __forceinline__ void stage_rows64(const half_t* __restrict__ src, int row0, int ld,
                                             int k0, half_t* dst, int nchunks, int tid) {
  for (int base = 0; base < nchunks; base += 256) {
    int ch  = base + tid;
    int row = ch >> 3, kc = ch & 7;
    int swz = kc ^ (row & 7);
    const half_t* g = src + (size_t)(row0 + row) * ld + k0 + swz * 8;
    half_t* l = dst + (size_t)(base + (tid & 192)) * 8;
    __builtin_amdgcn_global_load_lds(
        (const __attribute__((address_space(1))) uint32_t*)(const void*)g,
        (__attribute__((address_space(3))) uint32_t*)(void*)l, 16, 0, 0);
  }
}

__device__ __forceinline__ half8 frag32(const half_t* lds, int row, int chunk) {
  int slot = chunk ^ ((row >> 1) & 3);
  return *(const half8*)(lds + row * 32 + slot * 8);
}
__device__ __forceinline__ half8 frag64(const half_t* lds, int row, int chunk) {
  int slot = chunk ^ (row & 7);
  return *(const half8*)(lds + row * 64 + slot * 8);
}

// ---------------------------------------------------------------------------
// 1. Row-normalize U -> Vh (fp16). One block per row.
// ---------------------------------------------------------------------------
__global__ __launch_bounds__(256) void normalize_rows(const float* __restrict__ U,
                                                      half_t* __restrict__ Vh) {
  int r = blockIdx.x, t = threadIdx.x;
  float v[7];
  float s = 0.f;
#pragma unroll
  for (int i = 0; i < 7; ++i) {
    v[i] = U[(size_t)r * D_DIM + t + i * 256];
    s += v[i] * v[i];
  }
#pragma unroll
  for (int m = 32; m; m >>= 1) s += __shfl_xor(s, m);
  __shared__ float red[4];
  __shared__ float tot;
  if ((t & 63) == 0) red[t >> 6] = s;
  __syncthreads();
  if (t == 0) tot = 1.0f / sqrtf(red[0] + red[1] + red[2] + red[3]);
  __syncthreads();
  float rn = tot;
#pragma unroll
  for (int i = 0; i < 7; ++i)
    Vh[(size_t)r * D_DIM + t + i * 256] = (half_t)(v[i] * rn);
}

// ---------------------------------------------------------------------------
// 2. Transpose X (fp32, D x B) -> XT (fp16, B x D). 64x64 LDS tiles.
//    NOTE: launched AFTER the WtT GEMM — XT's first 6.4MB aliases Tinv.
// ---------------------------------------------------------------------------
__global__ __launch_bounds__(256) void transpose_x(const float* __restrict__ X,
                                                   half_t* __restrict__ XT) {
  __shared__ half_t t[64][68];
  int r0 = blockIdx.x * 64, c0 = blockIdx.y * 64;
  int tid = threadIdx.x;
#pragma unroll
  for (int i = 0; i < 16; ++i) {
    int f = tid + i * 256;
    int rr = f >> 6, cc = f & 63;
    t[rr][cc] = (half_t)X[(size_t)(r0 + rr) * B_DIM + c0 + cc];
  }
  __syncthreads();
#pragma unroll
  for (int i = 0; i < 16; ++i) {
    int f = tid + i * 256;
    int cc = f >> 6, rr = f & 63;
    XT[(size_t)(c0 + cc) * D_DIM + r0 + rr] = t[rr][cc];
  }
}

// ---------------------------------------------------------------------------
// 2b. Transpose Vh (fp16, D x D) -> VhT.
// ---------------------------------------------------------------------------
__global__ __launch_bounds__(256) void transpose_h(const half_t* __restrict__ Vh,
                                                   half_t* __restrict__ VhT) {
  __shared__ half_t t[64][68];
  int r0 = blockIdx.x * 64, c0 = blockIdx.y * 64;
  int tid = threadIdx.x;
#pragma unroll
  for (int i = 0; i < 16; ++i) {
    int f = tid + i * 256;
    int rr = f >> 6, cc = f & 63;
    t[rr][cc] = Vh[(size_t)(r0 + rr) * D_DIM + c0 + cc];
  }
  __syncthreads();
#pragma unroll
  for (int i = 0; i < 16; ++i) {
    int f = tid + i * 256;
    int cc = f >> 6, rr = f & 63;
    VhT[(size_t)(c0 + cc) * D_DIM + r0 + rr] = t[rr][cc];
  }
}

// ---------------------------------------------------------------------------
// 2c. Zero the block-level zero triangles (R10-verified): Tinv strict-UPPER
//     128-blocks and TinvT strict-LOWER 128-blocks (doubling GEMMs read them
//     as dense operands).
// ---------------------------------------------------------------------------
__global__ __launch_bounds__(256) void zero_tri(half_t* __restrict__ Tinv,
                                                half_t* __restrict__ TinvT) {
  int bc = blockIdx.x, br = blockIdx.y;
  int tid = threadIdx.x;
  half8 z = {};
  if (bc > br) {
    for (int it = 0; it < 8; ++it) {
      int ch = it * 256 + tid;
      int r = ch >> 4, c = (ch & 15) * 8;
      *(half8*)(Tinv + (size_t)(br * 128 + r) * D_DIM + bc * 128 + c) = z;
    }
  } else if (bc < br) {
    for (int it = 0; it < 8; ++it) {
      int ch = it * 256 + tid;
      int r = ch >> 4, c = (ch & 15) * 8;
      *(half8*)(TinvT + (size_t)(br * 128 + r) * D_DIM + bc * 128 + c) = z;
    }
  }
}

// ---------------------------------------------------------------------------
// 3. Big NT MFMA GEMM: 128x128 tile, 2-PHASE pipeline (R7-verified).
//    MODE 0 (gram->T16): triangular block skip; Ch = (c<r) ? 2*acc : 0  (fp16)
//    MODE 1 (Pf build):  Ch = (r==c ? 1 : 0) - acc                      (fp16)
//    MODE 2 (final):     Cf = acc (fp32). R11: by-FAST XCD ordering — the 14
//      M-tiles sharing one XT N-panel (459KB, fits 4MB XCD L2) run as
//      consecutive dispatch slots on ONE XCD -> panel fetched ~once from HBM
//      (R10 FETCH=206MB ~= XT x7; ideal ~36MB).
//    MODE 3 (WtT):       Ch = 2*acc; per-block K = n0+128 (triangular Tinv)
// ---------------------------------------------------------------------------
template <int MODE>
__global__ __launch_bounds__(256) void gemm_nt(const half_t* __restrict__ A,
                                               const half_t* __restrict__ B,
                                               float* __restrict__ Cf, half_t* __restrict__ Ch,
                                               int K, int lda, int ldb, int ldc) {
  int bx = blockIdx.x, by = blockIdx.y;
  if constexpr (MODE == 2) {
    // launched id -> XCD (id&7); within an XCD, sweep by (M-tiles) fastest so
    // concurrent CUs share one bx N-panel. Bijective for 64x14=896=8*8*14.
    int id = bx + gridDim.x * by;
    int xcd = id & 7, s = id >> 3;
    by = s % 14;
    bx = (s / 14) * 8 + xcd;
  }
  int m0 = by * 128, n0 = bx * 128;
  if constexpr (MODE == 0) { if (n0 > m0) return; }   // gram: lower+diag blocks only
  int Keff = K;
  if constexpr (MODE == 3) Keff = n0 + 128;           // Tinv rows r: k <= r only
  __shared__ half_t sA0[128 * 32], sB0[128 * 32];
  __shared__ half_t sA1[128 * 32], sB1[128 * 32];
  int tid = threadIdx.x, lane = tid & 63, wave = tid >> 6;
  int ln15 = lane & 15, quad = lane >> 4;
  int wr = (wave & 1) * 64, wc = (wave >> 1) * 64;
  float4v acc[4][4] = {};
  int KB = Keff / 32;                  // always even here (multiples of 4)
  auto compute = [&](const half_t* cA, const half_t* cB) {
    half8 af[4], bf[4];
#pragma unroll
    for (int i = 0; i < 4; ++i) af[i] = frag32(cA, wr + i * 16 + ln15, quad);
#pragma unroll
    for (int j = 0; j < 4; ++j) bf[j] = frag32(cB, wc + j * 16 + ln15, quad);
#pragma unroll
    for (int i = 0; i < 4; ++i)
#pragma unroll
      for (int j = 0; j < 4; ++j)
        acc[i][j] = __builtin_amdgcn_mfma_f32_16x16x32_f16(af[i], bf[j], acc[i][j], 0, 0, 0);
  };
  // prologue: stage tile 0 into buffer pair 0 (4 loads/thread)
  stage_rows(A, m0, lda, 0, sA0, 512, tid);
  stage_rows(B, n0, ldb, 0, sB0, 512, tid);
  for (int kb = 0; kb < KB; kb += 2) {
    stage_rows(A, m0, lda, (kb + 1) * 32, sA1, 512, tid);
    stage_rows(B, n0, ldb, (kb + 1) * 32, sB1, 512, tid);
    asm volatile("s_waitcnt vmcnt(4)" ::: "memory");
    __builtin_amdgcn_s_barrier();
    __builtin_amdgcn_sched_barrier(0);
    compute(sA0, sB0);
    __builtin_amdgcn_sched_barrier(0);
    __builtin_amdgcn_s_barrier();        // pair-0 reads done -> reusable
    if (kb + 2 < KB) {
      stage_rows(A, m0, lda, (kb + 2) * 32, sA0, 512, tid);
      stage_rows(B, n0, ldb, (kb + 2) * 32, sB0, 512, tid);
      asm volatile("s_waitcnt vmcnt(4)" ::: "memory");
    } else {
      asm volatile("s_waitcnt vmcnt(0)" ::: "memory");
    }
    __builtin_amdgcn_s_barrier();
    __builtin_amdgcn_sched_barrier(0);
    compute(sA1, sB1);
    __builtin_amdgcn_sched_barrier(0);
    __builtin_amdgcn_s_barrier();        // pair-1 reads done -> reusable
  }
#pragma unroll
  for (int i = 0; i < 4; ++i)
#pragma unroll
    for (int j = 0; j < 4; ++j)
#pragma unroll
      for (int rg = 0; rg < 4; ++rg) {
        int row = m0 + wr + i * 16 + quad * 4 + rg;
        int col = n0 + wc + j * 16 + ln15;
        size_t idx = (size_t)row * ldc + col;
        float v = acc[i][j][rg];
        if constexpr (MODE == 0) Ch[idx] = (col < row) ? (half_t)(2.0f * v) : (half_t)0.0f;
        else if constexpr (MODE == 1) Ch[idx] = (half_t)(((row == col) ? 1.0f : 0.0f) - v);
        else if constexpr (MODE == 3) Ch[idx] = (half_t)(2.0f * v);
        else Cf[idx] = v;
      }
}

// ---------------------------------------------------------------------------
// 4. Invert 14 diagonal 128x128 unit-lower-triangular blocks of T (from T16).
//    One wave per column; forward substitution. Writes BOTH Tinv and TinvT
//    diagonal blocks (full 128x128 incl. zeros above diag).
// ---------------------------------------------------------------------------
__global__ __launch_bounds__(256) void diag_inv(const half_t* __restrict__ T16,
                                                half_t* __restrict__ Tinv,
                                                half_t* __restrict__ TinvT) {
  int b = blockIdx.x >> 5;        // block 0..13
  int cg = blockIdx.x & 31;       // column group
  int wave = threadIdx.x >> 6, ln = threadIdx.x & 63;
  int c = cg * 4 + wave;          // this wave's column (0..127)
  __shared__ float Ls[128][128];
  __shared__ float xw[4][128];
  for (int i = 0; i < 64; ++i) {
    int f = threadIdx.x + i * 256;
    int r = f >> 7, cc = f & 127;
    Ls[r][cc] = (cc < r) ? (float)T16[(size_t)(b * 128 + r) * D_DIM + b * 128 + cc] : 0.0f;
  }
  __syncthreads();
  float xlo = (ln == 0) ? 1.f : 0.f, xhi = 0.f;
  for (int r = c + 1; r < 128; ++r) {
    float ta = 0.f;
    int j0 = c + ln, j1 = c + 64 + ln;
    if (j0 < r) ta += Ls[r][j0] * xlo;
    if (j1 < r) ta += Ls[r][j1] * xhi;
#pragma unroll
    for (int m = 32; m; m >>= 1) ta += __shfl_xor(ta, m);
    float xr = -ta;
    if (j0 == r) xlo = xr;
    if (j1 == r) xhi = xr;
    if (ln == 0) xw[wave][r] = xr;
  }
  __syncthreads();
  for (int rr = ln; rr < 128; rr += 64) {
    float val = (rr < c) ? 0.f : ((rr == c) ? 1.f : xw[wave][rr]);
    half_t hv = (half_t)val;
    Tinv[(size_t)(b * 128 + rr) * D_DIM + b * 128 + c] = hv;
    TinvT[(size_t)(b * 128 + c) * D_DIM + b * 128 + rr] = hv;
  }
}

// ---------------------------------------------------------------------------
// 5. Doubling-chain GEMM, 64x64 TILES (R11). R10's 128-tile chain ran its
//    big levels at 8-48 blocks (~0.2 blocks/CU, zero TLP) in the latency-
//    exposed ~2270cy/K-tile regime => chain ~115us for 3.8 GFLOP. 64-tiles
//    quadruple the block count (28..192 blocks) and 32KB LDS gives ~5
//    blocks/CU — TLP hides latency; operands are L2/L3-resident.
//    Semantics identical to R10's tinv_nt: R[m][n] = sum_k A[m][k]B[n][k],
//    z-batched; optional negate; O1 [m][n], optional O2 transposed [n][m].
// ---------------------------------------------------------------------------
__global__ __launch_bounds__(256) void tinv64(const half_t* __restrict__ A, int ldA, long long strA,
                                              const half_t* __restrict__ B, int ldB, long long strB,
                                              half_t* __restrict__ O1, int ldO1, long long strO1,
                                              half_t* __restrict__ O2, int ldO2, long long strO2,
                                              int K, int neg) {
  long long z = blockIdx.z;
  A += z * strA;
  B += z * strB;
  O1 += z * strO1;
  if (O2) O2 += z * strO2;
  int m0 = blockIdx.y * 64, n0 = blockIdx.x * 64;
  __shared__ half_t sA0[64 * 64], sB0[64 * 64];   // 8KB each
  __shared__ half_t sA1[64 * 64], sB1[64 * 64];   // 32KB total
  int tid = threadIdx.x, lane = tid & 63, wave = tid >> 6;
  int ln15 = lane & 15, quad = lane >> 4;
  int wr = (wave & 1) * 32, wc = (wave >> 1) * 32;
  float4v acc[2][2] = {};
  int KB = K / 64;                     // K in {128,256,512,768,1024}: KB even
  auto compute = [&](const half_t* cA, const half_t* cB) {
    half8 af[2], bf[2];
#pragma unroll
    for (int q = 0; q < 2; ++q) {
#pragma unroll
      for (int i = 0; i < 2; ++i) af[i] = frag64(cA, wr + i * 16 + ln15, q * 4 + quad);
#pragma unroll
      for (int j = 0; j < 2; ++j) bf[j] = frag64(cB, wc + j * 16 + ln15, q * 4 + quad);
#pragma unroll
      for (int i = 0; i < 2; ++i)
#pragma unroll
        for (int j = 0; j < 2; ++j)
          acc[i][j] = __builtin_amdgcn_mfma_f32_16x16x32_f16(af[i], bf[j], acc[i][j], 0, 0, 0);
    }
  };
  stage_rows64(A, m0, ldA, 0, sA0, 512, tid);
  stage_rows64(B, n0, ldB, 0, sB0, 512, tid);
  for (int kb = 0; kb < KB; kb += 2) {
    stage_rows64(A, m0, ldA, (kb + 1) * 64, sA1, 512, tid);
    stage_rows64(B, n0, ldB, (kb + 1) * 64, sB1, 512, tid);
    asm volatile("s_waitcnt vmcnt(4)" ::: "memory");
    __builtin_amdgcn_s_barrier();
    __builtin_amdgcn_sched_barrier(0);
    compute(sA0, sB0);
    __builtin_amdgcn_sched_barrier(0);
    __builtin_amdgcn_s_barrier();
    if (kb + 2 < KB) {
      stage_rows64(A, m0, ldA, (kb + 2) * 64, sA0, 512, tid);
      stage_rows64(B, n0, ldB, (kb + 2) * 64, sB0, 512, tid);
      asm volatile("s_waitcnt vmcnt(4)" ::: "memory");
    } else {
      asm volatile("s_waitcnt vmcnt(0)" ::: "memory");
    }
    __builtin_amdgcn_s_barrier();
    __builtin_amdgcn_sched_barrier(0);
    compute(sA1, sB1);
    __builtin_amdgcn_sched_barrier(0);
    __builtin_amdgcn_s_barrier();
  }
#pragma unroll
  for (int i = 0; i < 2; ++i)
#pragma unroll
    for (int j = 0; j < 2; ++j)
#pragma unroll
      for (int rg = 0; rg < 4; ++rg) {
        int m = m0 + wr + i * 16 + quad * 4 + rg;
        int n = n0 + wc + j * 16 + ln15;
        float v = acc[i][j][rg];
        if (neg) v = -v;
        half_t hv = (half_t)v;
        O1[(size_t)m * ldO1 + n] = hv;
        if (O2) O2[(size_t)n * ldO2 + m] = hv;
      }
}

// ---------------------------------------------------------------------------
extern "C" void kernel_launch(void* const* d_in, const int* in_sizes, int n_in,
                              void* d_out, int out_size, void* d_ws, size_t ws_size,
                              hipStream_t stream) {
  (void)in_sizes; (void)n_in; (void)out_size; (void)ws_size;
  const float* X = (const float*)d_in[0];   // (1792, 8192) fp32
  const float* U = (const float*)d_in[1];   // (1792, 1792) fp32
  float* out = (float*)d_out;               // (1792, 8192) fp32

  char* ws = (char*)d_ws;
  // Slab plan (61.47 MB, verified R10):
  //   [0 .. 29.36M)  XT (written LAST); Tinv aliases its first 6.42MB
  //   [29.36M..35.78M) Vh -> M1T scratch after gram+transpose_h
  //   [35.78M..42.21M) VhT
  //   [42.21M..48.63M) T16
  //   [48.63M..55.05M) WtT
  //   [55.05M..61.47M) TinvT -> Pf after the WtT GEMM
  half_t* Tinv  = (half_t*)(ws);
  half_t* XT    = (half_t*)(ws);
  half_t* Vh    = (half_t*)(ws + 29360128);
  half_t* scr   = Vh;                       // M1T scratch (<= 1.57MB used)
  half_t* VhT   = (half_t*)(ws + 35782656);
  half_t* T16   = (half_t*)(ws + 42205184);
  half_t* WtT   = (half_t*)(ws + 48627712);
  half_t* TinvT = (half_t*)(ws + 55050240);
  half_t* Pf    = TinvT;

  const int D = D_DIM;

  normalize_rows<<<dim3(D), dim3(256), 0, stream>>>(U, Vh);
  // T16 = 2*strict_tril(Vn Vn^T)
  gemm_nt<0><<<dim3(14, 14), dim3(256), 0, stream>>>(Vh, Vh, nullptr, T16, D, D, D, D);
  transpose_h<<<dim3(28, 28), dim3(256), 0, stream>>>(Vh, VhT);
  // 14 x 128 diagonal-block inverses -> Tinv/TinvT diag blocks
  diag_inv<<<dim3(448), dim3(256), 0, stream>>>(T16, Tinv, TinvT);
  // zero Tinv strict-upper / TinvT strict-lower blocks (R10-verified fix)
  zero_tri<<<dim3(14, 14), dim3(256), 0, stream>>>(Tinv, TinvT);

  // --- recursive doubling: fill strict-lower blocks of Tinv/TinvT ---
  // (64-tile grids: blocks = (N/64, M/64, pairs))
  // L1: 7 pairs of 128 (Aoff=256z, Boff=256z+128)
  {
    long long st = 256LL * D + 256;
    tinv64<<<dim3(2, 2, 7), dim3(256), 0, stream>>>(
        TinvT, D, st, T16 + 128LL * D, D, st, scr, 128, 16384, nullptr, 0, 0, 128, 0);
    tinv64<<<dim3(2, 2, 7), dim3(256), 0, stream>>>(
        scr, 128, 16384, Tinv + 128LL * D + 128, D, st,
        TinvT + 128, D, st, Tinv + 128LL * D, D, st, 128, 1);
  }
  // L2: 3 pairs of 256 (Aoff=512z, Boff=512z+256)
  {
    long long st = 512LL * D + 512;
    tinv64<<<dim3(4, 4, 3), dim3(256), 0, stream>>>(
        TinvT, D, st, T16 + 256LL * D, D, st, scr, 256, 65536, nullptr, 0, 0, 256, 0);
    tinv64<<<dim3(4, 4, 3), dim3(256), 0, stream>>>(
        scr, 256, 65536, Tinv + 256LL * D + 256, D, st,
        TinvT + 256, D, st, Tinv + 256LL * D, D, st, 256, 1);
  }
  // L3a: pair (512@0, 512@512)
  tinv64<<<dim3(8, 8, 1), dim3(256), 0, stream>>>(
      TinvT, D, 0, T16 + 512LL * D, D, 0, scr, 512, 0, nullptr, 0, 0, 512, 0);
  tinv64<<<dim3(8, 8, 1), dim3(256), 0, stream>>>(
      scr, 512, 0, Tinv + 512LL * D + 512, D, 0,
      TinvT + 512, D, 0, Tinv + 512LL * D, D, 0, 512, 1);
  // L3b: pair (512@1024, 256@1536): p=512, q=256
  tinv64<<<dim3(4, 8, 1), dim3(256), 0, stream>>>(
      TinvT + 1024LL * D + 1024, D, 0, T16 + 1536LL * D + 1024, D, 0,
      scr, 256, 0, nullptr, 0, 0, 512, 0);
  tinv64<<<dim3(4, 8, 1), dim3(256), 0, stream>>>(
      scr, 256, 0, Tinv + 1536LL * D + 1536, D, 0,
      TinvT + 1024LL * D + 1536, D, 0, Tinv + 1536LL * D + 1024, D, 0, 256, 1);
  // L4: pair (1024@0, 768@1024): p=1024, q=768
  tinv64<<<dim3(12, 16, 1), dim3(256), 0, stream>>>(
      TinvT, D, 0, T16 + 1024LL * D, D, 0, scr, 768, 0, nullptr, 0, 0, 1024, 0);
  tinv64<<<dim3(12, 16, 1), dim3(256), 0, stream>>>(
      scr, 768, 0, Tinv + 1024LL * D + 1024, D, 0,
      TinvT + 1024, D, 0, Tinv + 1024LL * D, D, 0, 768, 1);

  // WtT[m][r] = 2 * sum_{k<=r} VhT[m][k] * Tinv[r][k]   (triangular K)
  gemm_nt<3><<<dim3(14, 14), dim3(256), 0, stream>>>(VhT, Tinv, nullptr, WtT, 0, D, D, D);
  // Tinv now dead -> safe to build XT over its slab
  transpose_x<<<dim3(D / 64, B_DIM / 64), dim3(256), 0, stream>>>(X, XT);
  // Pf = I - Wt^T Vn   (Pf overlays dead TinvT)
  gemm_nt<1><<<dim3(14, 14), dim3(256), 0, stream>>>(WtT, VhT, nullptr, Pf, D, D, D, D);
  // out = Pf X
  gemm_nt<2><<<dim3(64, 14), dim3(256), 0, stream>>>(Pf, XT, out, nullptr, D, D, D, B_DIM);
}

// Round 12
// 382.509 us; speedup vs baseline: 1.2905x; 1.0371x over previous
//
#include <hip/hip_runtime.h>
#include <stdint.h>
#include <stddef.h>

typedef _Float16 half_t;
typedef _Float16 half8 __attribute__((ext_vector_type(8)));
typedef float float4v __attribute__((ext_vector_type(4)));

#define D_DIM 1792
#define B_DIM 8192

// ---------------------------------------------------------------------------
// Async global->LDS staging of ROWS*32 fp16 tile (rows along K, NT layout).
// slot = chunk ^ ((row>>1)&3): conflict-free (verified SQ_LDS_BANK_CONFLICT=0).
// ---------------------------------------------------------------------------
__device__ __forceinline__ void stage_rows(const half_t* __restrict__ src, int row0, int ld,
                                           int k0, half_t* dst, int nchunks, int tid) {
  for (int base = 0; base < nchunks; base += 256) {
    int ch  = base + tid;
    int row = ch >> 2, kc = ch & 3;
    int swz = kc ^ ((row >> 1) & 3);
    const half_t* g = src + (size_t)(row0 + row) * ld + k0 + swz * 8;
    half_t* l = dst + (size_t)(base + (tid & 192)) * 8;   // wave-uniform base; HW adds lane*16B
    __builtin_amdgcn_global_load_lds(
        (const __attribute__((address_space(1))) uint32_t*)(const void*)g,
        (__attribute__((address_space(3))) uint32_t*)(void*)l, 16, 0, 0);
  }
}

// FULL-LINE staging (128B/row = one aligned L2 line). slot = kc ^ (row&7).
__device__ __forceinline__ void stage_rows64(const half_t* __restrict__ src, int row0, int ld,
                                             int k0, half_t* dst, int nchunks, int tid) {
  for (int base = 0; base < nchunks; base += 256) {
    int ch  = base + tid;
    int row = ch >> 3, kc = ch & 7;
    int swz = kc ^ (row & 7);
    const half_t* g = src + (size_t)(row0 + row) * ld + k0 + swz * 8;
    half_t* l = dst + (size_t)(base + (tid & 192)) * 8;
    __builtin_amdgcn_global_load_lds(
        (const __attribute__((address_space(1))) uint32_t*)(const void*)g,
        (__attribute__((address_space(3))) uint32_t*)(void*)l, 16, 0, 0);
  }
}

__device__ __forceinline__ half8 frag32(const half_t* lds, int row, int chunk) {
  int slot = chunk ^ ((row >> 1) & 3);
  return *(const half8*)(lds + row * 32 + slot * 8);
}
__device__ __forceinline__ half8 frag64(const half_t* lds, int row, int chunk) {
  int slot = chunk ^ (row & 7);
  return *(const half8*)(lds + row * 64 + slot * 8);
}

// ---------------------------------------------------------------------------
// 1. Row-normalize U -> Vh (fp16). One block per row.
// ---------------------------------------------------------------------------
__global__ __launch_bounds__(256) void normalize_rows(const float* __restrict__ U,
                                                      half_t* __restrict__ Vh) {
  int r = blockIdx.x, t = threadIdx.x;
  float v[7];
  float s = 0.f;
#pragma unroll
  for (int i = 0; i < 7; ++i) {
    v[i] = U[(size_t)r * D_DIM + t + i * 256];
    s += v[i] * v[i];
  }
#pragma unroll
  for (int m = 32; m; m >>= 1) s += __shfl_xor(s, m);
  __shared__ float red[4];
  __shared__ float tot;
  if ((t & 63) == 0) red[t >> 6] = s;
  __syncthreads();
  if (t == 0) tot = 1.0f / sqrtf(red[0] + red[1] + red[2] + red[3]);
  __syncthreads();
  float rn = tot;
#pragma unroll
  for (int i = 0; i < 7; ++i)
    Vh[(size_t)r * D_DIM + t + i * 256] = (half_t)(v[i] * rn);
}

// ---------------------------------------------------------------------------
// 2. Transpose X (fp32, D x B) -> XT (fp16, B x D). 64x64 LDS tiles.
//    NOTE: launched AFTER the WtT GEMM — XT's first 6.4MB aliases Tinv.
// ---------------------------------------------------------------------------
__global__ __launch_bounds__(256) void transpose_x(const float* __restrict__ X,
                                                   half_t* __restrict__ XT) {
  __shared__ half_t t[64][68];
  int r0 = blockIdx.x * 64, c0 = blockIdx.y * 64;
  int tid = threadIdx.x;
#pragma unroll
  for (int i = 0; i < 16; ++i) {
    int f = tid + i * 256;
    int rr = f >> 6, cc = f & 63;
    t[rr][cc] = (half_t)X[(size_t)(r0 + rr) * B_DIM + c0 + cc];
  }
  __syncthreads();
#pragma unroll
  for (int i = 0; i < 16; ++i) {
    int f = tid + i * 256;
    int cc = f >> 6, rr = f & 63;
    XT[(size_t)(c0 + cc) * D_DIM + r0 + rr] = t[rr][cc];
  }
}

// ---------------------------------------------------------------------------
// 2b. Transpose Vh (fp16, D x D) -> VhT.
// ---------------------------------------------------------------------------
__global__ __launch_bounds__(256) void transpose_h(const half_t* __restrict__ Vh,
                                                   half_t* __restrict__ VhT) {
  __shared__ half_t t[64][68];
  int r0 = blockIdx.x * 64, c0 = blockIdx.y * 64;
  int tid = threadIdx.x;
#pragma unroll
  for (int i = 0; i < 16; ++i) {
    int f = tid + i * 256;
    int rr = f >> 6, cc = f & 63;
    t[rr][cc] = Vh[(size_t)(r0 + rr) * D_DIM + c0 + cc];
  }
  __syncthreads();
#pragma unroll
  for (int i = 0; i < 16; ++i) {
    int f = tid + i * 256;
    int cc = f >> 6, rr = f & 63;
    VhT[(size_t)(c0 + cc) * D_DIM + r0 + rr] = t[rr][cc];
  }
}

// ---------------------------------------------------------------------------
// 2c. Zero the block-level zero triangles (R10-verified): Tinv strict-UPPER
//     128-blocks and TinvT strict-LOWER 128-blocks.
// ---------------------------------------------------------------------------
__global__ __launch_bounds__(256) void zero_tri(half_t* __restrict__ Tinv,
                                                half_t* __restrict__ TinvT) {
  int bc = blockIdx.x, br = blockIdx.y;
  int tid = threadIdx.x;
  half8 z = {};
  if (bc > br) {
    for (int it = 0; it < 8; ++it) {
      int ch = it * 256 + tid;
      int r = ch >> 4, c = (ch & 15) * 8;
      *(half8*)(Tinv + (size_t)(br * 128 + r) * D_DIM + bc * 128 + c) = z;
    }
  } else if (bc < br) {
    for (int it = 0; it < 8; ++it) {
      int ch = it * 256 + tid;
      int r = ch >> 4, c = (ch & 15) * 8;
      *(half8*)(TinvT + (size_t)(br * 128 + r) * D_DIM + bc * 128 + c) = z;
    }
  }
}

// ---------------------------------------------------------------------------
// 3. Big NT MFMA GEMM (MODE 2 only now): 128x128 tile, 2-PHASE pipeline.
//    Cf = acc (fp32). by-FAST XCD ordering (R11-verified: FETCH 206->72MB).
// ---------------------------------------------------------------------------
template <int MODE>
__global__ __launch_bounds__(256) void gemm_nt(const half_t* __restrict__ A,
                                               const half_t* __restrict__ B,
                                               float* __restrict__ Cf, half_t* __restrict__ Ch,
                                               int K, int lda, int ldb, int ldc) {
  int bx = blockIdx.x, by = blockIdx.y;
  if constexpr (MODE == 2) {
    // id -> XCD (id&7); within an XCD, sweep by (M-tiles) fastest so
    // concurrent CUs share one bx N-panel. Bijective for 64x14=896=8*8*14.
    int id = bx + gridDim.x * by;
    int xcd = id & 7, s = id >> 3;
    by = s % 14;
    bx = (s / 14) * 8 + xcd;
  }
  int m0 = by * 128, n0 = bx * 128;
  __shared__ half_t sA0[128 * 32], sB0[128 * 32];
  __shared__ half_t sA1[128 * 32], sB1[128 * 32];
  int tid = threadIdx.x, lane = tid & 63, wave = tid >> 6;
  int ln15 = lane & 15, quad = lane >> 4;
  int wr = (wave & 1) * 64, wc = (wave >> 1) * 64;
  float4v acc[4][4] = {};
  int KB = K / 32;
  auto compute = [&](const half_t* cA, const half_t* cB) {
    half8 af[4], bf[4];
#pragma unroll
    for (int i = 0; i < 4; ++i) af[i] = frag32(cA, wr + i * 16 + ln15, quad);
#pragma unroll
    for (int j = 0; j < 4; ++j) bf[j] = frag32(cB, wc + j * 16 + ln15, quad);
#pragma unroll
    for (int i = 0; i < 4; ++i)
#pragma unroll
      for (int j = 0; j < 4; ++j)
        acc[i][j] = __builtin_amdgcn_mfma_f32_16x16x32_f16(af[i], bf[j], acc[i][j], 0, 0, 0);
  };
  stage_rows(A, m0, lda, 0, sA0, 512, tid);
  stage_rows(B, n0, ldb, 0, sB0, 512, tid);
  for (int kb = 0; kb < KB; kb += 2) {
    stage_rows(A, m0, lda, (kb + 1) * 32, sA1, 512, tid);
    stage_rows(B, n0, ldb, (kb + 1) * 32, sB1, 512, tid);
    asm volatile("s_waitcnt vmcnt(4)" ::: "memory");
    __builtin_amdgcn_s_barrier();
    __builtin_amdgcn_sched_barrier(0);
    compute(sA0, sB0);
    __builtin_amdgcn_sched_barrier(0);
    __builtin_amdgcn_s_barrier();
    if (kb + 2 < KB) {
      stage_rows(A, m0, lda, (kb + 2) * 32, sA0, 512, tid);
      stage_rows(B, n0, ldb, (kb + 2) * 32, sB0, 512, tid);
      asm volatile("s_waitcnt vmcnt(4)" ::: "memory");
    } else {
      asm volatile("s_waitcnt vmcnt(0)" ::: "memory");
    }
    __builtin_amdgcn_s_barrier();
    __builtin_amdgcn_sched_barrier(0);
    compute(sA1, sB1);
    __builtin_amdgcn_sched_barrier(0);
    __builtin_amdgcn_s_barrier();
  }
#pragma unroll
  for (int i = 0; i < 4; ++i)
#pragma unroll
    for (int j = 0; j < 4; ++j)
#pragma unroll
      for (int rg = 0; rg < 4; ++rg) {
        int row = m0 + wr + i * 16 + quad * 4 + rg;
        int col = n0 + wc + j * 16 + ln15;
        Cf[(size_t)row * ldc + col] = acc[i][j][rg];
      }
}

// ---------------------------------------------------------------------------
// 3b. 64x64-TILE NT GEMM for the D x D products (R12). The 128-tile versions
//     ran 196 blocks on 256 CUs (0.77/CU, 60 CUs idle, latency-exposed).
//     64-tiles give 784 blocks (~3/CU) + 16KB LDS -> TLP hides latency;
//     operands (6.4MB) are L2/L3-resident so the halved arithmetic
//     intensity is absorbed by cache BW. Structure = verified R7 2-phase.
//    MODE 0 (gram->T16): block skip n0>m0; Ch = (c<r) ? 2*acc : 0
//    MODE 1 (Pf build):  Ch = (r==c ? 1 : 0) - acc
//    MODE 3 (WtT):       Ch = 2*acc; Keff = n0+64 (triangular Tinv; KB even)
// ---------------------------------------------------------------------------
template <int MODE>
__global__ __launch_bounds__(256) void gemm64(const half_t* __restrict__ A,
                                              const half_t* __restrict__ B,
                                              half_t* __restrict__ Ch,
                                              int K, int lda, int ldb, int ldc) {
  int m0 = blockIdx.y * 64, n0 = blockIdx.x * 64;
  if constexpr (MODE == 0) { if (n0 > m0) return; }
  int Keff = K;
  if constexpr (MODE == 3) Keff = n0 + 64;            // KB = 2*bx+2: even
  __shared__ half_t sA0[64 * 32], sB0[64 * 32];
  __shared__ half_t sA1[64 * 32], sB1[64 * 32];       // 16KB total
  int tid = threadIdx.x, lane = tid & 63, wave = tid >> 6;
  int ln15 = lane & 15, quad = lane >> 4;
  int wr = (wave & 1) * 32, wc = (wave >> 1) * 32;
  float4v acc[2][2] = {};
  int KB = Keff / 32;                                 // even for all modes
  auto compute = [&](const half_t* cA, const half_t* cB) {
    half8 af[2], bf[2];
#pragma unroll
    for (int i = 0; i < 2; ++i) af[i] = frag32(cA, wr + i * 16 + ln15, quad);
#pragma unroll
    for (int j = 0; j < 2; ++j) bf[j] = frag32(cB, wc + j * 16 + ln15, quad);
#pragma unroll
    for (int i = 0; i < 2; ++i)
#pragma unroll
      for (int j = 0; j < 2; ++j)
        acc[i][j] = __builtin_amdgcn_mfma_f32_16x16x32_f16(af[i], bf[j], acc[i][j], 0, 0, 0);
  };
  stage_rows(A, m0, lda, 0, sA0, 256, tid);
  stage_rows(B, n0, ldb, 0, sB0, 256, tid);
  for (int kb = 0; kb < KB; kb += 2) {
    stage_rows(A, m0, lda, (kb + 1) * 32, sA1, 256, tid);
    stage_rows(B, n0, ldb, (kb + 1) * 32, sB1, 256, tid);
    asm volatile("s_waitcnt vmcnt(2)" ::: "memory");
    __builtin_amdgcn_s_barrier();
    __builtin_amdgcn_sched_barrier(0);
    compute(sA0, sB0);
    __builtin_amdgcn_sched_barrier(0);
    __builtin_amdgcn_s_barrier();
    if (kb + 2 < KB) {
      stage_rows(A, m0, lda, (kb + 2) * 32, sA0, 256, tid);
      stage_rows(B, n0, ldb, (kb + 2) * 32, sB0, 256, tid);
      asm volatile("s_waitcnt vmcnt(2)" ::: "memory");
    } else {
      asm volatile("s_waitcnt vmcnt(0)" ::: "memory");
    }
    __builtin_amdgcn_s_barrier();
    __builtin_amdgcn_sched_barrier(0);
    compute(sA1, sB1);
    __builtin_amdgcn_sched_barrier(0);
    __builtin_amdgcn_s_barrier();
  }
#pragma unroll
  for (int i = 0; i < 2; ++i)
#pragma unroll
    for (int j = 0; j < 2; ++j)
#pragma unroll
      for (int rg = 0; rg < 4; ++rg) {
        int row = m0 + wr + i * 16 + quad * 4 + rg;
        int col = n0 + wc + j * 16 + ln15;
        size_t idx = (size_t)row * ldc + col;
        float v = acc[i][j][rg];
        if constexpr (MODE == 0) Ch[idx] = (col < row) ? (half_t)(2.0f * v) : (half_t)0.0f;
        else if constexpr (MODE == 1) Ch[idx] = (half_t)(((row == col) ? 1.0f : 0.0f) - v);
        else Ch[idx] = (half_t)(2.0f * v);
      }
}

// ---------------------------------------------------------------------------
// 4. Invert 14 diagonal 128x128 unit-lower-triangular blocks of T (from T16).
//    One wave per column; forward substitution. Writes BOTH Tinv and TinvT
//    diagonal blocks (full 128x128 incl. zeros above diag).
// ---------------------------------------------------------------------------
__global__ __launch_bounds__(256) void diag_inv(const half_t* __restrict__ T16,
                                                half_t* __restrict__ Tinv,
                                                half_t* __restrict__ TinvT) {
  int b = blockIdx.x >> 5;        // block 0..13
  int cg = blockIdx.x & 31;       // column group
  int wave = threadIdx.x >> 6, ln = threadIdx.x & 63;
  int c = cg * 4 + wave;          // this wave's column (0..127)
  __shared__ float Ls[128][128];
  __shared__ float xw[4][128];
  for (int i = 0; i < 64; ++i) {
    int f = threadIdx.x + i * 256;
    int r = f >> 7, cc = f & 127;
    Ls[r][cc] = (cc < r) ? (float)T16[(size_t)(b * 128 + r) * D_DIM + b * 128 + cc] : 0.0f;
  }
  __syncthreads();
  float xlo = (ln == 0) ? 1.f : 0.f, xhi = 0.f;
  for (int r = c + 1; r < 128; ++r) {
    float ta = 0.f;
    int j0 = c + ln, j1 = c + 64 + ln;
    if (j0 < r) ta += Ls[r][j0] * xlo;
    if (j1 < r) ta += Ls[r][j1] * xhi;
#pragma unroll
    for (int m = 32; m; m >>= 1) ta += __shfl_xor(ta, m);
    float xr = -ta;
    if (j0 == r) xlo = xr;
    if (j1 == r) xhi = xr;
    if (ln == 0) xw[wave][r] = xr;
  }
  __syncthreads();
  for (int rr = ln; rr < 128; rr += 64) {
    float val = (rr < c) ? 0.f : ((rr == c) ? 1.f : xw[wave][rr]);
    half_t hv = (half_t)val;
    Tinv[(size_t)(b * 128 + rr) * D_DIM + b * 128 + c] = hv;
    TinvT[(size_t)(b * 128 + c) * D_DIM + b * 128 + rr] = hv;
  }
}

// ---------------------------------------------------------------------------
// 5. Doubling-chain GEMM, 64x64 tiles (R11-verified). R[m][n]=sum A[m][k]B[n][k],
//    z-batched; optional negate; O1 [m][n], optional O2 transposed [n][m].
// ---------------------------------------------------------------------------
__global__ __launch_bounds__(256) void tinv64(const half_t* __restrict__ A, int ldA, long long strA,
                                              const half_t* __restrict__ B, int ldB, long long strB,
                                              half_t* __restrict__ O1, int ldO1, long long strO1,
                                              half_t* __restrict__ O2, int ldO2, long long strO2,
                                              int K, int neg) {
  long long z = blockIdx.z;
  A += z * strA;
  B += z * strB;
  O1 += z * strO1;
  if (O2) O2 += z * strO2;
  int m0 = blockIdx.y * 64, n0 = blockIdx.x * 64;
  __shared__ half_t sA0[64 * 64], sB0[64 * 64];
  __shared__ half_t sA1[64 * 64], sB1[64 * 64];
  int tid = threadIdx.x, lane = tid & 63, wave = tid >> 6;
  int ln15 = lane & 15, quad = lane >> 4;
  int wr = (wave & 1) * 32, wc = (wave >> 1) * 32;
  float4v acc[2][2] = {};
  int KB = K / 64;
  auto compute = [&](const half_t* cA, const half_t* cB) {
    half8 af[2], bf[2];
#pragma unroll
    for (int q = 0; q < 2; ++q) {
#pragma unroll
      for (int i = 0; i < 2; ++i) af[i] = frag64(cA, wr + i * 16 + ln15, q * 4 + quad);
#pragma unroll
      for (int j = 0; j < 2; ++j) bf[j] = frag64(cB, wc + j * 16 + ln15, q * 4 + quad);
#pragma unroll
      for (int i = 0; i < 2; ++i)
#pragma unroll
        for (int j = 0; j < 2; ++j)
          acc[i][j] = __builtin_amdgcn_mfma_f32_16x16x32_f16(af[i], bf[j], acc[i][j], 0, 0, 0);
    }
  };
  stage_rows64(A, m0, ldA, 0, sA0, 512, tid);
  stage_rows64(B, n0, ldB, 0, sB0, 512, tid);
  for (int kb = 0; kb < KB; kb += 2) {
    stage_rows64(A, m0, ldA, (kb + 1) * 64, sA1, 512, tid);
    stage_rows64(B, n0, ldB, (kb + 1) * 64, sB1, 512, tid);
    asm volatile("s_waitcnt vmcnt(4)" ::: "memory");
    __builtin_amdgcn_s_barrier();
    __builtin_amdgcn_sched_barrier(0);
    compute(sA0, sB0);
    __builtin_amdgcn_sched_barrier(0);
    __builtin_amdgcn_s_barrier();
    if (kb + 2 < KB) {
      stage_rows64(A, m0, ldA, (kb + 2) * 64, sA0, 512, tid);
      stage_rows64(B, n0, ldB, (kb + 2) * 64, sB0, 512, tid);
      asm volatile("s_waitcnt vmcnt(4)" ::: "memory");
    } else {
      asm volatile("s_waitcnt vmcnt(0)" ::: "memory");
    }
    __builtin_amdgcn_s_barrier();
    __builtin_amdgcn_sched_barrier(0);
    compute(sA1, sB1);
    __builtin_amdgcn_sched_barrier(0);
    __builtin_amdgcn_s_barrier();
  }
#pragma unroll
  for (int i = 0; i < 2; ++i)
#pragma unroll
    for (int j = 0; j < 2; ++j)
#pragma unroll
      for (int rg = 0; rg < 4; ++rg) {
        int m = m0 + wr + i * 16 + quad * 4 + rg;
        int n = n0 + wc + j * 16 + ln15;
        float v = acc[i][j][rg];
        if (neg) v = -v;
        half_t hv = (half_t)v;
        O1[(size_t)m * ldO1 + n] = hv;
        if (O2) O2[(size_t)n * ldO2 + m] = hv;
      }
}

// ---------------------------------------------------------------------------
extern "C" void kernel_launch(void* const* d_in, const int* in_sizes, int n_in,
                              void* d_out, int out_size, void* d_ws, size_t ws_size,
                              hipStream_t stream) {
  (void)in_sizes; (void)n_in; (void)out_size; (void)ws_size;
  const float* X = (const float*)d_in[0];   // (1792, 8192) fp32
  const float* U = (const float*)d_in[1];   // (1792, 1792) fp32
  float* out = (float*)d_out;               // (1792, 8192) fp32

  char* ws = (char*)d_ws;
  // Slab plan (61.47 MB, verified R10/R11):
  //   [0 .. 29.36M)  XT (written LAST); Tinv aliases its first 6.42MB
  //   [29.36M..35.78M) Vh -> M1T scratch after gram+transpose_h
  //   [35.78M..42.21M) VhT
  //   [42.21M..48.63M) T16
  //   [48.63M..55.05M) WtT
  //   [55.05M..61.47M) TinvT -> Pf after the WtT GEMM
  half_t* Tinv  = (half_t*)(ws);
  half_t* XT    = (half_t*)(ws);
  half_t* Vh    = (half_t*)(ws + 29360128);
  half_t* scr   = Vh;                       // M1T scratch (<= 1.57MB used)
  half_t* VhT   = (half_t*)(ws + 35782656);
  half_t* T16   = (half_t*)(ws + 42205184);
  half_t* WtT   = (half_t*)(ws + 48627712);
  half_t* TinvT = (half_t*)(ws + 55050240);
  half_t* Pf    = TinvT;

  const int D = D_DIM;

  normalize_rows<<<dim3(D), dim3(256), 0, stream>>>(U, Vh);
  // T16 = 2*strict_tril(Vn Vn^T)   (64-tile, 784 blocks, TLP-rich)
  gemm64<0><<<dim3(28, 28), dim3(256), 0, stream>>>(Vh, Vh, T16, D, D, D, D);
  transpose_h<<<dim3(28, 28), dim3(256), 0, stream>>>(Vh, VhT);
  // 14 x 128 diagonal-block inverses -> Tinv/TinvT diag blocks
  diag_inv<<<dim3(448), dim3(256), 0, stream>>>(T16, Tinv, TinvT);
  // zero Tinv strict-upper / TinvT strict-lower blocks
  zero_tri<<<dim3(14, 14), dim3(256), 0, stream>>>(Tinv, TinvT);

  // --- recursive doubling: fill strict-lower blocks of Tinv/TinvT ---
  // L1: 7 pairs of 128 (Aoff=256z, Boff=256z+128)
  {
    long long st = 256LL * D + 256;
    tinv64<<<dim3(2, 2, 7), dim3(256), 0, stream>>>(
        TinvT, D, st, T16 + 128LL * D, D, st, scr, 128, 16384, nullptr, 0, 0, 128, 0);
    tinv64<<<dim3(2, 2, 7), dim3(256), 0, stream>>>(
        scr, 128, 16384, Tinv + 128LL * D + 128, D, st,
        TinvT + 128, D, st, Tinv + 128LL * D, D, st, 128, 1);
  }
  // L2: 3 pairs of 256 (Aoff=512z, Boff=512z+256)
  {
    long long st = 512LL * D + 512;
    tinv64<<<dim3(4, 4, 3), dim3(256), 0, stream>>>(
        TinvT, D, st, T16 + 256LL * D, D, st, scr, 256, 65536, nullptr, 0, 0, 256, 0);
    tinv64<<<dim3(4, 4, 3), dim3(256), 0, stream>>>(
        scr, 256, 65536, Tinv + 256LL * D + 256, D, st,
        TinvT + 256, D, st, Tinv + 256LL * D, D, st, 256, 1);
  }
  // L3a: pair (512@0, 512@512)
  tinv64<<<dim3(8, 8, 1), dim3(256), 0, stream>>>(
      TinvT, D, 0, T16 + 512LL * D, D, 0, scr, 512, 0, nullptr, 0, 0, 512, 0);
  tinv64<<<dim3(8, 8, 1), dim3(256), 0, stream>>>(
      scr, 512, 0, Tinv + 512LL * D + 512, D, 0,
      TinvT + 512, D, 0, Tinv + 512LL * D, D, 0, 512, 1);
  // L3b: pair (512@1024, 256@1536): p=512, q=256
  tinv64<<<dim3(4, 8, 1), dim3(256), 0, stream>>>(
      TinvT + 1024LL * D + 1024, D, 0, T16 + 1536LL * D + 1024, D, 0,
      scr, 256, 0, nullptr, 0, 0, 512, 0);
  tinv64<<<dim3(4, 8, 1), dim3(256), 0, stream>>>(
      scr, 256, 0, Tinv + 1536LL * D + 1536, D, 0,
      TinvT + 1024LL * D + 1536, D, 0, Tinv + 1536LL * D + 1024, D, 0, 256, 1);
  // L4: pair (1024@0, 768@1024): p=1024, q=768
  tinv64<<<dim3(12, 16, 1), dim3(256), 0, stream>>>(
      TinvT, D, 0, T16 + 1024LL * D, D, 0, scr, 768, 0, nullptr, 0, 0, 1024, 0);
  tinv64<<<dim3(12, 16, 1), dim3(256), 0, stream>>>(
      scr, 768, 0, Tinv + 1024LL * D + 1024, D, 0,
      TinvT + 1024, D, 0, Tinv + 1024LL * D, D, 0, 768, 1);

  // WtT[m][r] = 2 * sum_{k<=r} VhT[m][k] * Tinv[r][k]   (triangular K, 64-tile)
  gemm64<3><<<dim3(28, 28), dim3(256), 0, stream>>>(VhT, Tinv, WtT, 0, D, D, D);
  // Tinv now dead -> safe to build XT over its slab
  transpose_x<<<dim3(D / 64, B_DIM / 64), dim3(256), 0, stream>>>(X, XT);
  // Pf = I - Wt^T Vn   (64-tile; Pf overlays dead TinvT)
  gemm64<1><<<dim3(28, 28), dim3(256), 0, stream>>>(WtT, VhT, Pf, D, D, D, D);
  // out = Pf X
  gemm_nt<2><<<dim3(64, 14), dim3(256), 0, stream>>>(Pf, XT, out, nullptr, D, D, D, B_DIM);
}

// Round 13
// 363.384 us; speedup vs baseline: 1.3584x; 1.0526x over previous
//
#include <hip/hip_runtime.h>
#include <stdint.h>
#include <stddef.h>

typedef _Float16 half_t;
typedef _Float16 half8 __attribute__((ext_vector_type(8)));
typedef float float4v __attribute__((ext_vector_type(4)));

#define D_DIM 1792
#define B_DIM 8192

// ---------------------------------------------------------------------------
// Async global->LDS staging of ROWS*32 fp16 tile (rows along K, NT layout).
// slot = chunk ^ ((row>>1)&3): conflict-free (verified SQ_LDS_BANK_CONFLICT=0).
// ---------------------------------------------------------------------------
__device__ __forceinline__ void stage_rows(const half_t* __restrict__ src, int row0, int ld,
                                           int k0, half_t* dst, int nchunks, int tid) {
  for (int base = 0; base < nchunks; base += 256) {
    int ch  = base + tid;
    int row = ch >> 2, kc = ch & 3;
    int swz = kc ^ ((row >> 1) & 3);
    const half_t* g = src + (size_t)(row0 + row) * ld + k0 + swz * 8;
    half_t* l = dst + (size_t)(base + (tid & 192)) * 8;   // wave-uniform base; HW adds lane*16B
    __builtin_amdgcn_global_load_lds(
        (const __attribute__((address_space(1))) uint32_t*)(const void*)g,
        (__attribute__((address_space(3))) uint32_t*)(void*)l, 16, 0, 0);
  }
}

// FULL-LINE staging (128B/row = one aligned L2 line). slot = kc ^ (row&7).
// 256-thread version (tinv64).
__device__ __forceinline__ void stage_rows64(const half_t* __restrict__ src, int row0, int ld,
                                             int k0, half_t* dst, int nchunks, int tid) {
  for (int base = 0; base < nchunks; base += 256) {
    int ch  = base + tid;
    int row = ch >> 3, kc = ch & 7;
    int swz = kc ^ (row & 7);
    const half_t* g = src + (size_t)(row0 + row) * ld + k0 + swz * 8;
    half_t* l = dst + (size_t)(base + (tid & 192)) * 8;
    __builtin_amdgcn_global_load_lds(
        (const __attribute__((address_space(1))) uint32_t*)(const void*)g,
        (__attribute__((address_space(3))) uint32_t*)(void*)l, 16, 0, 0);
  }
}

// 512-thread full-line staging (gemm_out): 256 rows x 64 halves = 2048 chunks.
__device__ __forceinline__ void stage512(const half_t* __restrict__ src, int row0, int ld,
                                         int k0, half_t* dst, int tid) {
  for (int base = 0; base < 2048; base += 512) {
    int ch  = base + tid;
    int row = ch >> 3, kc = ch & 7;
    int swz = kc ^ (row & 7);
    const half_t* g = src + (size_t)(row0 + row) * ld + k0 + swz * 8;
    half_t* l = dst + (size_t)(base + (tid & 448)) * 8;   // wave-uniform; HW adds lane*16B
    __builtin_amdgcn_global_load_lds(
        (const __attribute__((address_space(1))) uint32_t*)(const void*)g,
        (__attribute__((address_space(3))) uint32_t*)(void*)l, 16, 0, 0);
  }
}

__device__ __forceinline__ half8 frag32(const half_t* lds, int row, int chunk) {
  int slot = chunk ^ ((row >> 1) & 3);
  return *(const half8*)(lds + row * 32 + slot * 8);
}
__device__ __forceinline__ half8 frag64(const half_t* lds, int row, int chunk) {
  int slot = chunk ^ (row & 7);
  return *(const half8*)(lds + row * 64 + slot * 8);
}

// ---------------------------------------------------------------------------
// 1. Row-normalize U -> Vh (fp16). One block per row.
// ---------------------------------------------------------------------------
__global__ __launch_bounds__(256) void normalize_rows(const float* __restrict__ U,
                                                      half_t* __restrict__ Vh) {
  int r = blockIdx.x, t = threadIdx.x;
  float v[7];
  float s = 0.f;
#pragma unroll
  for (int i = 0; i < 7; ++i) {
    v[i] = U[(size_t)r * D_DIM + t + i * 256];
    s += v[i] * v[i];
  }
#pragma unroll
  for (int m = 32; m; m >>= 1) s += __shfl_xor(s, m);
  __shared__ float red[4];
  __shared__ float tot;
  if ((t & 63) == 0) red[t >> 6] = s;
  __syncthreads();
  if (t == 0) tot = 1.0f / sqrtf(red[0] + red[1] + red[2] + red[3]);
  __syncthreads();
  float rn = tot;
#pragma unroll
  for (int i = 0; i < 7; ++i)
    Vh[(size_t)r * D_DIM + t + i * 256] = (half_t)(v[i] * rn);
}

// ---------------------------------------------------------------------------
// 2. Transpose X (fp32, D x B) -> XT (fp16, B x D). 64x64 LDS tiles.
//    NOTE: launched AFTER the WtT GEMM — XT's first 6.4MB aliases Tinv.
// ---------------------------------------------------------------------------
__global__ __launch_bounds__(256) void transpose_x(const float* __restrict__ X,
                                                   half_t* __restrict__ XT) {
  __shared__ half_t t[64][68];
  int r0 = blockIdx.x * 64, c0 = blockIdx.y * 64;
  int tid = threadIdx.x;
#pragma unroll
  for (int i = 0; i < 16; ++i) {
    int f = tid + i * 256;
    int rr = f >> 6, cc = f & 63;
    t[rr][cc] = (half_t)X[(size_t)(r0 + rr) * B_DIM + c0 + cc];
  }
  __syncthreads();
#pragma unroll
  for (int i = 0; i < 16; ++i) {
    int f = tid + i * 256;
    int cc = f >> 6, rr = f & 63;
    XT[(size_t)(c0 + cc) * D_DIM + r0 + rr] = t[rr][cc];
  }
}

// ---------------------------------------------------------------------------
// 2b. Transpose Vh (fp16, D x D) -> VhT.
// ---------------------------------------------------------------------------
__global__ __launch_bounds__(256) void transpose_h(const half_t* __restrict__ Vh,
                                                   half_t* __restrict__ VhT) {
  __shared__ half_t t[64][68];
  int r0 = blockIdx.x * 64, c0 = blockIdx.y * 64;
  int tid = threadIdx.x;
#pragma unroll
  for (int i = 0; i < 16; ++i) {
    int f = tid + i * 256;
    int rr = f >> 6, cc = f & 63;
    t[rr][cc] = Vh[(size_t)(r0 + rr) * D_DIM + c0 + cc];
  }
  __syncthreads();
#pragma unroll
  for (int i = 0; i < 16; ++i) {
    int f = tid + i * 256;
    int cc = f >> 6, rr = f & 63;
    VhT[(size_t)(c0 + cc) * D_DIM + r0 + rr] = t[rr][cc];
  }
}

// ---------------------------------------------------------------------------
// 2c. Zero the block-level zero triangles (R10-verified): Tinv strict-UPPER
//     128-blocks and TinvT strict-LOWER 128-blocks.
// ---------------------------------------------------------------------------
__global__ __launch_bounds__(256) void zero_tri(half_t* __restrict__ Tinv,
                                                half_t* __restrict__ TinvT) {
  int bc = blockIdx.x, br = blockIdx.y;
  int tid = threadIdx.x;
  half8 z = {};
  if (bc > br) {
    for (int it = 0; it < 8; ++it) {
      int ch = it * 256 + tid;
      int r = ch >> 4, c = (ch & 15) * 8;
      *(half8*)(Tinv + (size_t)(br * 128 + r) * D_DIM + bc * 128 + c) = z;
    }
  } else if (bc < br) {
    for (int it = 0; it < 8; ++it) {
      int ch = it * 256 + tid;
      int r = ch >> 4, c = (ch & 15) * 8;
      *(half8*)(TinvT + (size_t)(br * 128 + r) * D_DIM + bc * 128 + c) = z;
    }
  }
}

// ---------------------------------------------------------------------------
// 3. OUTPUT GEMM (R13): 256x256 tile, BK=64, 8 waves (512 thr), counted-
//    vmcnt double-buffer. R12 measured the 128x32 structure at 591 TF
//    (stall-dominated: neither BW- nor MFMA-bound). Here: 64 MFMA/wave per
//    barrier-pair (4x more), boundary wait vmcnt(8) keeps the NEXT K-tile's
//    8 loads in flight across the barrier (T4 — the isolated +38-73% lever).
//    Staging/read pair = verified full-line swizzle (bank-conflict 0).
//    No sched_barrier around compute (m141), no setprio (null on 2-phase).
//    out[m][n] = sum_k Pf[m][k] * XT[n][k]  (fp32 C).
// ---------------------------------------------------------------------------
__global__ __launch_bounds__(512) void gemm_out(const half_t* __restrict__ A,
                                                const half_t* __restrict__ B,
                                                float* __restrict__ C,
                                                int K, int lda, int ldb, int ldc) {
  // by-fast XCD ordering over 224 = 8 XCDs x (4 N-groups x 7 M). 7 consecutive
  // slots on one XCD share the same 918KB B-panel (L2-resident).
  int id = blockIdx.x;
  int xcd = id & 7, s = id >> 3;       // s in 0..27
  int by = s % 7;                      // M-tile (fast)
  int bx = (s / 7) * 8 + xcd;          // N-tile 0..31
  int m0 = by * 256, n0 = bx * 256;
  __shared__ half_t sA[2][256 * 64];   // 2 x 32KB
  __shared__ half_t sB[2][256 * 64];   // 2 x 32KB  => 128KB total
  int tid = threadIdx.x, lane = tid & 63;
  int wv = tid >> 6, wr = wv & 1, wc = wv >> 1;   // wave -> (M-half, N-quarter)
  int ln15 = lane & 15, quad = lane >> 4;
  float4v acc[8][4] = {};
  int NT = K / 64;                     // 28
  // prologue: two tiles in flight (8 loads/thread each)
  stage512(A, m0, lda, 0, &sA[0][0], tid);
  stage512(B, n0, ldb, 0, &sB[0][0], tid);
  stage512(A, m0, lda, 64, &sA[1][0], tid);
  stage512(B, n0, ldb, 64, &sB[1][0], tid);
  for (int t = 0; t < NT; ++t) {
    if (t + 1 < NT) asm volatile("s_waitcnt vmcnt(8)" ::: "memory");
    else            asm volatile("s_waitcnt vmcnt(0)" ::: "memory");
    __builtin_amdgcn_s_barrier();      // every wave waited for its tile-t loads
    int b = t & 1;
    const half_t* cA = &sA[b][0];
    const half_t* cB = &sB[b][0];
    half8 bf[4][2];
#pragma unroll
    for (int j = 0; j < 4; ++j)
#pragma unroll
      for (int q = 0; q < 2; ++q)
        bf[j][q] = frag64(cB, wc * 64 + j * 16 + ln15, q * 4 + quad);
#pragma unroll
    for (int i = 0; i < 8; ++i) {
      half8 a0 = frag64(cA, wr * 128 + i * 16 + ln15, quad);
      half8 a1 = frag64(cA, wr * 128 + i * 16 + ln15, 4 + quad);
#pragma unroll
      for (int j = 0; j < 4; ++j) {
        acc[i][j] = __builtin_amdgcn_mfma_f32_16x16x32_f16(a0, bf[j][0], acc[i][j], 0, 0, 0);
        acc[i][j] = __builtin_amdgcn_mfma_f32_16x16x32_f16(a1, bf[j][1], acc[i][j], 0, 0, 0);
      }
    }
    __builtin_amdgcn_s_barrier();      // all reads of buf b complete
    if (t + 2 < NT) {                  // refill buf b for tile t+2
      stage512(A, m0, lda, (t + 2) * 64, &sA[b][0], tid);
      stage512(B, n0, ldb, (t + 2) * 64, &sB[b][0], tid);
    }
  }
#pragma unroll
  for (int i = 0; i < 8; ++i)
#pragma unroll
    for (int j = 0; j < 4; ++j)
#pragma unroll
      for (int rg = 0; rg < 4; ++rg) {
        int row = m0 + wr * 128 + i * 16 + quad * 4 + rg;
        int col = n0 + wc * 64 + j * 16 + ln15;
        C[(size_t)row * ldc + col] = acc[i][j][rg];
      }
}

// ---------------------------------------------------------------------------
// 3b. 64x64-TILE NT GEMM for the D x D products (R12-verified).
//    MODE 0 (gram->T16): block skip n0>m0; Ch = (c<r) ? 2*acc : 0
//    MODE 1 (Pf build):  Ch = (r==c ? 1 : 0) - acc
//    MODE 3 (WtT):       Ch = 2*acc; Keff = n0+64 (triangular Tinv; KB even)
// ---------------------------------------------------------------------------
template <int MODE>
__global__ __launch_bounds__(256) void gemm64(const half_t* __restrict__ A,
                                              const half_t* __restrict__ B,
                                              half_t* __restrict__ Ch,
                                              int K, int lda, int ldb, int ldc) {
  int m0 = blockIdx.y * 64, n0 = blockIdx.x * 64;
  if constexpr (MODE == 0) { if (n0 > m0) return; }
  int Keff = K;
  if constexpr (MODE == 3) Keff = n0 + 64;            // KB = 2*bx+2: even
  __shared__ half_t sA0[64 * 32], sB0[64 * 32];
  __shared__ half_t sA1[64 * 32], sB1[64 * 32];       // 16KB total
  int tid = threadIdx.x, lane = tid & 63, wave = tid >> 6;
  int ln15 = lane & 15, quad = lane >> 4;
  int wr = (wave & 1) * 32, wc = (wave >> 1) * 32;
  float4v acc[2][2] = {};
  int KB = Keff / 32;                                 // even for all modes
  auto compute = [&](const half_t* cA, const half_t* cB) {
    half8 af[2], bf[2];
#pragma unroll
    for (int i = 0; i < 2; ++i) af[i] = frag32(cA, wr + i * 16 + ln15, quad);
#pragma unroll
    for (int j = 0; j < 2; ++j) bf[j] = frag32(cB, wc + j * 16 + ln15, quad);
#pragma unroll
    for (int i = 0; i < 2; ++i)
#pragma unroll
      for (int j = 0; j < 2; ++j)
        acc[i][j] = __builtin_amdgcn_mfma_f32_16x16x32_f16(af[i], bf[j], acc[i][j], 0, 0, 0);
  };
  stage_rows(A, m0, lda, 0, sA0, 256, tid);
  stage_rows(B, n0, ldb, 0, sB0, 256, tid);
  for (int kb = 0; kb < KB; kb += 2) {
    stage_rows(A, m0, lda, (kb + 1) * 32, sA1, 256, tid);
    stage_rows(B, n0, ldb, (kb + 1) * 32, sB1, 256, tid);
    asm volatile("s_waitcnt vmcnt(2)" ::: "memory");
    __builtin_amdgcn_s_barrier();
    __builtin_amdgcn_sched_barrier(0);
    compute(sA0, sB0);
    __builtin_amdgcn_sched_barrier(0);
    __builtin_amdgcn_s_barrier();
    if (kb + 2 < KB) {
      stage_rows(A, m0, lda, (kb + 2) * 32, sA0, 256, tid);
      stage_rows(B, n0, ldb, (kb + 2) * 32, sB0, 256, tid);
      asm volatile("s_waitcnt vmcnt(2)" ::: "memory");
    } else {
      asm volatile("s_waitcnt vmcnt(0)" ::: "memory");
    }
    __builtin_amdgcn_s_barrier();
    __builtin_amdgcn_sched_barrier(0);
    compute(sA1, sB1);
    __builtin_amdgcn_sched_barrier(0);
    __builtin_amdgcn_s_barrier();
  }
#pragma unroll
  for (int i = 0; i < 2; ++i)
#pragma unroll
    for (int j = 0; j < 2; ++j)
#pragma unroll
      for (int rg = 0; rg < 4; ++rg) {
        int row = m0 + wr + i * 16 + quad * 4 + rg;
        int col = n0 + wc + j * 16 + ln15;
        size_t idx = (size_t)row * ldc + col;
        float v = acc[i][j][rg];
        if constexpr (MODE == 0) Ch[idx] = (col < row) ? (half_t)(2.0f * v) : (half_t)0.0f;
        else if constexpr (MODE == 1) Ch[idx] = (half_t)(((row == col) ? 1.0f : 0.0f) - v);
        else Ch[idx] = (half_t)(2.0f * v);
      }
}

// ---------------------------------------------------------------------------
// 4. Invert 14 diagonal 128x128 unit-lower-triangular blocks of T (from T16).
//    One wave per column; forward substitution. Writes BOTH Tinv and TinvT
//    diagonal blocks (full 128x128 incl. zeros above diag).
// ---------------------------------------------------------------------------
__global__ __launch_bounds__(256) void diag_inv(const half_t* __restrict__ T16,
                                                half_t* __restrict__ Tinv,
                                                half_t* __restrict__ TinvT) {
  int b = blockIdx.x >> 5;        // block 0..13
  int cg = blockIdx.x & 31;       // column group
  int wave = threadIdx.x >> 6, ln = threadIdx.x & 63;
  int c = cg * 4 + wave;          // this wave's column (0..127)
  __shared__ float Ls[128][128];
  __shared__ float xw[4][128];
  for (int i = 0; i < 64; ++i) {
    int f = threadIdx.x + i * 256;
    int r = f >> 7, cc = f & 127;
    Ls[r][cc] = (cc < r) ? (float)T16[(size_t)(b * 128 + r) * D_DIM + b * 128 + cc] : 0.0f;
  }
  __syncthreads();
  float xlo = (ln == 0) ? 1.f : 0.f, xhi = 0.f;
  for (int r = c + 1; r < 128; ++r) {
    float ta = 0.f;
    int j0 = c + ln, j1 = c + 64 + ln;
    if (j0 < r) ta += Ls[r][j0] * xlo;
    if (j1 < r) ta += Ls[r][j1] * xhi;
#pragma unroll
    for (int m = 32; m; m >>= 1) ta += __shfl_xor(ta, m);
    float xr = -ta;
    if (j0 == r) xlo = xr;
    if (j1 == r) xhi = xr;
    if (ln == 0) xw[wave][r] = xr;
  }
  __syncthreads();
  for (int rr = ln; rr < 128; rr += 64) {
    float val = (rr < c) ? 0.f : ((rr == c) ? 1.f : xw[wave][rr]);
    half_t hv = (half_t)val;
    Tinv[(size_t)(b * 128 + rr) * D_DIM + b * 128 + c] = hv;
    TinvT[(size_t)(b * 128 + c) * D_DIM + b * 128 + rr] = hv;
  }
}

// ---------------------------------------------------------------------------
// 5. Doubling-chain GEMM, 64x64 tiles (R11-verified). R[m][n]=sum A[m][k]B[n][k],
//    z-batched; optional negate; O1 [m][n], optional O2 transposed [n][m].
// ---------------------------------------------------------------------------
__global__ __launch_bounds__(256) void tinv64(const half_t* __restrict__ A, int ldA, long long strA,
                                              const half_t* __restrict__ B, int ldB, long long strB,
                                              half_t* __restrict__ O1, int ldO1, long long strO1,
                                              half_t* __restrict__ O2, int ldO2, long long strO2,
                                              int K, int neg) {
  long long z = blockIdx.z;
  A += z * strA;
  B += z * strB;
  O1 += z * strO1;
  if (O2) O2 += z * strO2;
  int m0 = blockIdx.y * 64, n0 = blockIdx.x * 64;
  __shared__ half_t sA0[64 * 64], sB0[64 * 64];
  __shared__ half_t sA1[64 * 64], sB1[64 * 64];
  int tid = threadIdx.x, lane = tid & 63, wave = tid >> 6;
  int ln15 = lane & 15, quad = lane >> 4;
  int wr = (wave & 1) * 32, wc = (wave >> 1) * 32;
  float4v acc[2][2] = {};
  int KB = K / 64;
  auto compute = [&](const half_t* cA, const half_t* cB) {
    half8 af[2], bf[2];
#pragma unroll
    for (int q = 0; q < 2; ++q) {
#pragma unroll
      for (int i = 0; i < 2; ++i) af[i] = frag64(cA, wr + i * 16 + ln15, q * 4 + quad);
#pragma unroll
      for (int j = 0; j < 2; ++j) bf[j] = frag64(cB, wc + j * 16 + ln15, q * 4 + quad);
#pragma unroll
      for (int i = 0; i < 2; ++i)
#pragma unroll
        for (int j = 0; j < 2; ++j)
          acc[i][j] = __builtin_amdgcn_mfma_f32_16x16x32_f16(af[i], bf[j], acc[i][j], 0, 0, 0);
    }
  };
  stage_rows64(A, m0, ldA, 0, sA0, 512, tid);
  stage_rows64(B, n0, ldB, 0, sB0, 512, tid);
  for (int kb = 0; kb < KB; kb += 2) {
    stage_rows64(A, m0, ldA, (kb + 1) * 64, sA1, 512, tid);
    stage_rows64(B, n0, ldB, (kb + 1) * 64, sB1, 512, tid);
    asm volatile("s_waitcnt vmcnt(4)" ::: "memory");
    __builtin_amdgcn_s_barrier();
    __builtin_amdgcn_sched_barrier(0);
    compute(sA0, sB0);
    __builtin_amdgcn_sched_barrier(0);
    __builtin_amdgcn_s_barrier();
    if (kb + 2 < KB) {
      stage_rows64(A, m0, ldA, (kb + 2) * 64, sA0, 512, tid);
      stage_rows64(B, n0, ldB, (kb + 2) * 64, sB0, 512, tid);
      asm volatile("s_waitcnt vmcnt(4)" ::: "memory");
    } else {
      asm volatile("s_waitcnt vmcnt(0)" ::: "memory");
    }
    __builtin_amdgcn_s_barrier();
    __builtin_amdgcn_sched_barrier(0);
    compute(sA1, sB1);
    __builtin_amdgcn_sched_barrier(0);
    __builtin_amdgcn_s_barrier();
  }
#pragma unroll
  for (int i = 0; i < 2; ++i)
#pragma unroll
    for (int j = 0; j < 2; ++j)
#pragma unroll
      for (int rg = 0; rg < 4; ++rg) {
        int m = m0 + wr + i * 16 + quad * 4 + rg;
        int n = n0 + wc + j * 16 + ln15;
        float v = acc[i][j][rg];
        if (neg) v = -v;
        half_t hv = (half_t)v;
        O1[(size_t)m * ldO1 + n] = hv;
        if (O2) O2[(size_t)n * ldO2 + m] = hv;
      }
}

// ---------------------------------------------------------------------------
extern "C" void kernel_launch(void* const* d_in, const int* in_sizes, int n_in,
                              void* d_out, int out_size, void* d_ws, size_t ws_size,
                              hipStream_t stream) {
  (void)in_sizes; (void)n_in; (void)out_size; (void)ws_size;
  const float* X = (const float*)d_in[0];   // (1792, 8192) fp32
  const float* U = (const float*)d_in[1];   // (1792, 1792) fp32
  float* out = (float*)d_out;               // (1792, 8192) fp32

  char* ws = (char*)d_ws;
  // Slab plan (61.47 MB, verified R10-R12):
  //   [0 .. 29.36M)  XT (written LAST); Tinv aliases its first 6.42MB
  //   [29.36M..35.78M) Vh -> M1T scratch after gram+transpose_h
  //   [35.78M..42.21M) VhT
  //   [42.21M..48.63M) T16
  //   [48.63M..55.05M) WtT
  //   [55.05M..61.47M) TinvT -> Pf after the WtT GEMM
  half_t* Tinv  = (half_t*)(ws);
  half_t* XT    = (half_t*)(ws);
  half_t* Vh    = (half_t*)(ws + 29360128);
  half_t* scr   = Vh;                       // M1T scratch (<= 1.57MB used)
  half_t* VhT   = (half_t*)(ws + 35782656);
  half_t* T16   = (half_t*)(ws + 42205184);
  half_t* WtT   = (half_t*)(ws + 48627712);
  half_t* TinvT = (half_t*)(ws + 55050240);
  half_t* Pf    = TinvT;

  const int D = D_DIM;

  normalize_rows<<<dim3(D), dim3(256), 0, stream>>>(U, Vh);
  // T16 = 2*strict_tril(Vn Vn^T)   (64-tile, TLP-rich)
  gemm64<0><<<dim3(28, 28), dim3(256), 0, stream>>>(Vh, Vh, T16, D, D, D, D);
  transpose_h<<<dim3(28, 28), dim3(256), 0, stream>>>(Vh, VhT);
  // 14 x 128 diagonal-block inverses -> Tinv/TinvT diag blocks
  diag_inv<<<dim3(448), dim3(256), 0, stream>>>(T16, Tinv, TinvT);
  // zero Tinv strict-upper / TinvT strict-lower blocks
  zero_tri<<<dim3(14, 14), dim3(256), 0, stream>>>(Tinv, TinvT);

  // --- recursive doubling: fill strict-lower blocks of Tinv/TinvT ---
  // L1: 7 pairs of 128 (Aoff=256z, Boff=256z+128)
  {
    long long st = 256LL * D + 256;
    tinv64<<<dim3(2, 2, 7), dim3(256), 0, stream>>>(
        TinvT, D, st, T16 + 128LL * D, D, st, scr, 128, 16384, nullptr, 0, 0, 128, 0);
    tinv64<<<dim3(2, 2, 7), dim3(256), 0, stream>>>(
        scr, 128, 16384, Tinv + 128LL * D + 128, D, st,
        TinvT + 128, D, st, Tinv + 128LL * D, D, st, 128, 1);
  }
  // L2: 3 pairs of 256 (Aoff=512z, Boff=512z+256)
  {
    long long st = 512LL * D + 512;
    tinv64<<<dim3(4, 4, 3), dim3(256), 0, stream>>>(
        TinvT, D, st, T16 + 256LL * D, D, st, scr, 256, 65536, nullptr, 0, 0, 256, 0);
    tinv64<<<dim3(4, 4, 3), dim3(256), 0, stream>>>(
        scr, 256, 65536, Tinv + 256LL * D + 256, D, st,
        TinvT + 256, D, st, Tinv + 256LL * D, D, st, 256, 1);
  }
  // L3a: pair (512@0, 512@512)
  tinv64<<<dim3(8, 8, 1), dim3(256), 0, stream>>>(
      TinvT, D, 0, T16 + 512LL * D, D, 0, scr, 512, 0, nullptr, 0, 0, 512, 0);
  tinv64<<<dim3(8, 8, 1), dim3(256), 0, stream>>>(
      scr, 512, 0, Tinv + 512LL * D + 512, D, 0,
      TinvT + 512, D, 0, Tinv + 512LL * D, D, 0, 512, 1);
  // L3b: pair (512@1024, 256@1536): p=512, q=256
  tinv64<<<dim3(4, 8, 1), dim3(256), 0, stream>>>(
      TinvT + 1024LL * D + 1024, D, 0, T16 + 1536LL * D + 1024, D, 0,
      scr, 256, 0, nullptr, 0, 0, 512, 0);
  tinv64<<<dim3(4, 8, 1), dim3(256), 0, stream>>>(
      scr, 256, 0, Tinv + 1536LL * D + 1536, D, 0,
      TinvT + 1024LL * D + 1536, D, 0, Tinv + 1536LL * D + 1024, D, 0, 256, 1);
  // L4: pair (1024@0, 768@1024): p=1024, q=768
  tinv64<<<dim3(12, 16, 1), dim3(256), 0, stream>>>(
      TinvT, D, 0, T16 + 1024LL * D, D, 0, scr, 768, 0, nullptr, 0, 0, 1024, 0);
  tinv64<<<dim3(12, 16, 1), dim3(256), 0, stream>>>(
      scr, 768, 0, Tinv + 1024LL * D + 1024, D, 0,
      TinvT + 1024, D, 0, Tinv + 1024LL * D, D, 0, 768, 1);

  // WtT[m][r] = 2 * sum_{k<=r} VhT[m][k] * Tinv[r][k]   (triangular K, 64-tile)
  gemm64<3><<<dim3(28, 28), dim3(256), 0, stream>>>(VhT, Tinv, WtT, 0, D, D, D);
  // Tinv now dead -> safe to build XT over its slab
  transpose_x<<<dim3(D / 64, B_DIM / 64), dim3(256), 0, stream>>>(X, XT);
  // Pf = I - Wt^T Vn   (64-tile; Pf overlays dead TinvT)
  gemm64<1><<<dim3(28, 28), dim3(256), 0, stream>>>(WtT, VhT, Pf, D, D, D, D);
  // out = Pf X   (256^2 / BK=64 / 8-wave counted-vmcnt pipeline)
  gemm_out<<<dim3(224), dim3(512), 0, stream>>>(Pf, XT, out, D, D, D, B_DIM);
}